// Round 8
// baseline (1028.173 us; speedup 1.0000x reference)
//
#include <hip/hip_runtime.h>
#include <hip/hip_bf16.h>
#include <math.h>

#define HWD 262144   // 64*64*64

typedef __attribute__((ext_vector_type(8))) short bf16x8;   // 8 bf16 (4 VGPRs)
typedef __attribute__((ext_vector_type(16))) float f32x16;  // MFMA 32x32 accumulator

__device__ inline unsigned short bfu(float f) {
    __hip_bfloat16 h = __float2bfloat16(f);
    return *reinterpret_cast<unsigned short*>(&h);
}

// ---------------- prep: weights -> bf16 GEMM layout A[ks 72][oc 128][kk 16]; w_map -> Wb bf16 ----
// K order: k = ((g*3+r)*3+s)*64 + z,  ks=k>>4, kk=k&15.
__global__ void k_prep(const float* __restrict__ w_t, const float* __restrict__ w_c,
                       const float* __restrict__ w_map,
                       __hip_bfloat16* __restrict__ A_t, __hip_bfloat16* __restrict__ A_c,
                       __hip_bfloat16* __restrict__ Wb) {
    int i = blockIdx.x * 256 + threadIdx.x;
    if (i < 147456) {
        int kk = i & 15, oc = (i >> 4) & 127, ks = i >> 11;
        int z4 = ks & 3, kq = ks >> 2;          // kq = (g*3+r)*3+s in [0,18)
        int g = kq / 9, tap = kq - 9 * g;       // tap = r*3+s
        int z = z4 * 16 + kk;
        // w_t (128,2,64,3,3): ((o*2+g)*64+kh)*9 + tap,  z=kh
        A_t[i] = __float2bfloat16(w_t[((oc * 2 + g) * 64 + z) * 9 + tap]);
        // w_c (128,2,3,3,64): ((o*2+g)*9+tap)*64 + kd,  z=kd
        A_c[i] = __float2bfloat16(w_c[((oc * 2 + g) * 9 + tap) * 64 + z]);
    }
    if (i < 8192) {
        Wb[i] = __float2bfloat16(w_map[i]);   // w_map is (C,2C) row-major = [c][k]
    }
}

__device__ inline void pack_row_bf16(__hip_bfloat16* dst, const float* src) {
    unsigned short u[16];
#pragma unroll
    for (int j = 0; j < 16; ++j) u[j] = bfu(src[j]);
    uint4* q = reinterpret_cast<uint4*>(dst);
    q[0] = *reinterpret_cast<const uint4*>(&u[0]);
    q[1] = *reinterpret_cast<const uint4*>(&u[8]);
}

// ---------------- transpose x (B,N,C) -> Xc bf16, z4-plane layout [cg][z4][h*w][16] ------------
__global__ void k_trans_c(const float* __restrict__ x, __hip_bfloat16* __restrict__ Xc) {
    __shared__ unsigned short tile[256][68];
    int b = blockIdx.y;
    long n0 = (long)blockIdx.x * 256;
    int t = threadIdx.x;
    const float4* xp4 = (const float4*)(x + ((long)b * HWD + n0) * 64);
#pragma unroll
    for (int i = 0; i < 16; ++i) {
        int f4i = i * 256 + t;
        float4 v = xp4[f4i];
        int nl = f4i >> 4, c4 = (f4i & 15) * 4;
        ushort4 u;
        u.x = bfu(v.x); u.y = bfu(v.y); u.z = bfu(v.z); u.w = bfu(v.w);
        *(ushort4*)&tile[nl][c4] = u;
    }
    __syncthreads();
    int c = t >> 2, hwl = t & 3;
    int hw0 = blockIdx.x * 4;
    __hip_bfloat16* dst0 = Xc + (long)(b * 64 + c) * HWD + (long)(hw0 + hwl) * 16;
#pragma unroll
    for (int z4 = 0; z4 < 4; ++z4) {
        unsigned short u[16];
#pragma unroll
        for (int j = 0; j < 16; ++j) u[j] = tile[hwl * 64 + z4 * 16 + j][c];
        __hip_bfloat16* dst = dst0 + z4 * 65536;
        *(uint4*)dst = *(const uint4*)&u[0];
        *(uint4*)(dst + 8) = *(const uint4*)&u[8];
    }
}

// ---------------- transpose x -> Xt bf16, z4-plane layout [cg][z4][w*d][16] (inner 16 = h) -----
__global__ void k_trans_t(const float* __restrict__ x, __hip_bfloat16* __restrict__ Xt) {
    __shared__ unsigned short tile[256][68];   // [wdl*64+h][c]
    int b = blockIdx.y;
    int wd0 = blockIdx.x * 4;
    int t = threadIdx.x;
    const float* xb = x + (long)b * HWD * 64 + (long)wd0 * 64;
#pragma unroll
    for (int i = 0; i < 16; ++i) {
        int idx = i * 256 + t;              // float4 id over 64 h x 64 f
        int h = idx >> 6, f = idx & 63;     // per h: 4 wd x 64 c = 1KB contiguous
        float4 v = *(const float4*)(xb + (long)h * 262144 + f * 4);
        int wdl = f >> 4, c4 = (f & 15) * 4;
        ushort4 u;
        u.x = bfu(v.x); u.y = bfu(v.y); u.z = bfu(v.z); u.w = bfu(v.w);
        *(ushort4*)&tile[wdl * 64 + h][c4] = u;
    }
    __syncthreads();
    int c = t >> 2, wdl = t & 3;
    __hip_bfloat16* dst0 = Xt + (long)(b * 64 + c) * HWD + (long)(wd0 + wdl) * 16;
#pragma unroll
    for (int z4 = 0; z4 < 4; ++z4) {
        unsigned short u[16];
#pragma unroll
        for (int j = 0; j < 16; ++j) u[j] = tile[wdl * 64 + z4 * 16 + j][c];
        __hip_bfloat16* dst = dst0 + z4 * 65536;
        *(uint4*)dst = *(const uint4*)&u[0];
        *(uint4*)(dst + 8) = *(const uint4*)&u[8];
    }
}

// ---------------- unified MFMA conv v5: 128x256 block tile, B LDS-staged per kq --------------
// R7 diagnosis: all conv variants pinned at 22-24% MfmaUtil because VM bytes/MFMA ~ 1KB
// (every fragment re-fetched through L1 per MFMA; per-CU TA/L1 pipe ~2x oversubscribed).
// v5 halves bytes/MFMA to 0.5KB: block = 128 oc x 256 n (4 p-rows), 4 waves x (64x128)
// = 8 accs/wave; B staged ONCE per block per kq (32KB, dense 16B/lane loads) into
// half-plane LDS [z4][khalf][row] (conflict-free b128 reads), double-buffered, ONE
// barrier per kq (18 total), loads issued before the 32-MFMA cluster (T14). A direct
// from L1 (panel shared chip-wide). Numerics: identical k-order (ks 0..71) as before.
__global__ __launch_bounds__(256, 2) void k_conv_mfma(
        const __hip_bfloat16* __restrict__ X, const __hip_bfloat16* __restrict__ Aglob,
        const float* __restrict__ bias, float* __restrict__ Out) {
    int L = blockIdx.x;                       // 1024 = 64 grp * 16 pt
    int grp = (L & 7) * 8 + ((L >> 3) >> 4);  // XCD r handles grps [r*8, r*8+8)
    int pt = (L >> 3) & 15;
    int b = grp >> 5, ch = grp & 31;
    int p0 = pt * 4;
    const short* Xg = (const short*)(X + ((long)(b * 64 + 2 * ch)) * HWD);
    const short* Ag = (const short*)Aglob;
    int t = threadIdx.x;
    int lane = t & 63, wv = t >> 6;
    int O0 = (wv >> 1) * 64;              // wave oc base
    int N0 = (wv & 1) * 128;              // wave n base (128-wide)
    int lrow = lane & 31, lq = lane >> 5;

    // LDS: [buf][z4][khalf][256 rows x 8 shorts] = 64 KB
    __shared__ __align__(16) short Bsm[2][4][2][2048];

    f32x16 acc[2][4];
#pragma unroll
    for (int m = 0; m < 2; ++m)
#pragma unroll
        for (int j = 0; j < 4; ++j) acc[m][j] = (f32x16){0};

    // staging: thread covers (row0 = t>>1, row1 = 128 + (t>>1)), khalf = t&1.
    int srow0 = t >> 1, srow1 = 128 + (t >> 1), shalf = t & 1;
    const uint4 zero4 = {0u, 0u, 0u, 0u};
    uint4 ld[8];   // [z4][row0/row1]

    auto stage_load = [&](int kq) {
        int g = (kq >= 9) ? 1 : 0;
        int tap = kq - 9 * g;
        int r = tap / 3, s = tap - 3 * r;
        int pr0 = srow0 >> 6, q0 = srow0 & 63;
        int pr1 = srow1 >> 6, q1 = srow1 & 63;
        int pp0 = p0 + pr0 + r - 1, qq0 = q0 + s - 1;
        int pp1 = p0 + pr1 + r - 1, qq1 = q1 + s - 1;
        bool ok0 = ((unsigned)pp0 < 64u) && ((unsigned)qq0 < 64u);
        bool ok1 = ((unsigned)pp1 < 64u) && ((unsigned)qq1 < 64u);
        const short* px0 = Xg + (long)g * HWD + (pp0 * 64 + qq0) * 16 + shalf * 8;
        const short* px1 = Xg + (long)g * HWD + (pp1 * 64 + qq1) * 16 + shalf * 8;
#pragma unroll
        for (int z4 = 0; z4 < 4; ++z4) {
            ld[2 * z4 + 0] = ok0 ? *(const uint4*)(px0 + z4 * 65536) : zero4;
            ld[2 * z4 + 1] = ok1 ? *(const uint4*)(px1 + z4 * 65536) : zero4;
        }
    };
    auto stage_write = [&](int buf) {
#pragma unroll
        for (int z4 = 0; z4 < 4; ++z4) {
            *(uint4*)&Bsm[buf][z4][shalf][srow0 * 8] = ld[2 * z4 + 0];
            *(uint4*)&Bsm[buf][z4][shalf][srow1 * 8] = ld[2 * z4 + 1];
        }
    };

    stage_load(0);
    stage_write(0);
    __syncthreads();

    int buf = 0;
    for (int kq = 0; kq < 18; ++kq) {
        if (kq < 17) stage_load(kq + 1);       // in flight across the MFMA cluster
#pragma unroll
        for (int z4 = 0; z4 < 4; ++z4) {
            int ks = kq * 4 + z4;
            const short* Apk = Ag + ks * 2048 + (O0 + lrow) * 16 + lq * 8;
            uint4 a0u = *(const uint4*)(Apk);
            uint4 a1u = *(const uint4*)(Apk + 512);
            bf16x8 a0 = *(bf16x8*)&a0u;
            bf16x8 a1 = *(bf16x8*)&a1u;
#pragma unroll
            for (int j = 0; j < 4; ++j) {
                bf16x8 bj = *(const bf16x8*)&Bsm[buf][z4][lq][(N0 + 32 * j + lrow) * 8];
                acc[0][j] = __builtin_amdgcn_mfma_f32_32x32x16_bf16(a0, bj, acc[0][j], 0, 0, 0);
                acc[1][j] = __builtin_amdgcn_mfma_f32_32x32x16_bf16(a1, bj, acc[1][j], 0, 0, 0);
            }
        }
        if (kq < 17) {
            stage_write(buf ^ 1);              // buf^1 not read this kq; laggards gated by barrier
            __syncthreads();
            buf ^= 1;
        }
    }

    // store: C/D layout col(n)=lane&31, row(oc)=(reg&3)+8*(reg>>2)+4*lq
    long base0 = ((long)(b * 64 + 2 * ch)) * HWD + (long)p0 * 64;
#pragma unroll
    for (int reg = 0; reg < 16; ++reg) {
        int row = (reg & 3) + 8 * (reg >> 2) + 4 * lq;
#pragma unroll
        for (int m = 0; m < 2; ++m) {
            int oc = O0 + 32 * m + row;
            long cb = base0 + (long)(oc >> 6) * HWD + (long)(oc & 63) * 4096;
            float bs = bias[oc];
#pragma unroll
            for (int j = 0; j < 4; ++j) {
                int nn = N0 + 32 * j + lrow;   // flat within the 4 p-rows
                Out[cb + nn] = acc[m][j][reg] + bs;
            }
        }
    }
}

// ---------------- attn v2: At[b,c,h,w2,d] = sum_w Cc[b,c,w2,h,w] * T[b,c,w2,w,d] (bf16 out) ----
__global__ __launch_bounds__(128) void k_attn(const float* __restrict__ Cc,
        const float* __restrict__ T, __hip_bfloat16* __restrict__ At) {
    __shared__ float As[64][65];   // [h][w]
    __shared__ float Bs[64][64];   // [w][d]
    int bc = blockIdx.x >> 6, w2 = blockIdx.x & 63;
    const float4* Ap4 = (const float4*)(Cc + ((long)bc * 64 + w2) * 4096);
    const float4* Bp4 = (const float4*)(T + ((long)bc * 64 + w2) * 4096);
    int t = threadIdx.x;
#pragma unroll
    for (int i = 0; i < 8; ++i) {
        int f = i * 128 + t;               // float4 id, 1024 total
        int r = f >> 4, q4 = (f & 15) * 4;
        float4 v = Ap4[f];
        As[r][q4 + 0] = v.x; As[r][q4 + 1] = v.y; As[r][q4 + 2] = v.z; As[r][q4 + 3] = v.w;
        float4 w = Bp4[f];
        *(float4*)&Bs[r][q4] = w;
    }
    __syncthreads();
    int h2 = t >> 2, dg = (t & 3) * 16;
    f32x16 acc0 = {0}, acc1 = {0};
    for (int k = 0; k < 64; ++k) {
        float a0 = As[h2][k];
        float a1 = As[h2 + 32][k];
        const float* br = &Bs[k][dg];
#pragma unroll
        for (int i = 0; i < 16; ++i) {
            acc0[i] = fmaf(a0, br[i], acc0[i]);
            acc1[i] = fmaf(a1, br[i], acc1[i]);
        }
    }
    float tmp[16];
    __hip_bfloat16* Ab = At + (long)bc * HWD + (long)h2 * 4096 + w2 * 64 + dg;
#pragma unroll
    for (int i = 0; i < 16; ++i) tmp[i] = acc0[i];
    pack_row_bf16(Ab, tmp);
#pragma unroll
    for (int i = 0; i < 16; ++i) tmp[i] = acc1[i];
    pack_row_bf16(Ab + 32L * 4096, tmp);
}

// ---------------- f: F[b,c,h,w,d] = sum_w2 Cc[b,c,w2,h,w] * T[b,c,w2,w,d] (bf16 out) ----
__global__ __launch_bounds__(512, 4) void k_f(const float* __restrict__ Cc,
        const float* __restrict__ T, __hip_bfloat16* __restrict__ F) {
    __shared__ float As[16][64][8];   // [kk][h][w]        32 KB
    __shared__ float Bs[16][8][68];   // [kk][w][d(+pad)]  34 KB
    int L = blockIdx.x;               // 1024 = 128 bc * 8 wt
    int xcd = L & 7, j = L >> 3;      // j 0..127
    int bc = xcd * 16 + (j >> 3), wt = j & 7;
    const float* Ab = Cc + (long)bc * HWD + wt * 8;
    const float* Bb = T + (long)bc * HWD + wt * 8 * 64;
    int t = threadIdx.x;
    int w = t & 7, h = t >> 3;
    f32x16 acc0 = {0}, acc1 = {0}, acc2 = {0}, acc3 = {0};

    for (int w2c = 0; w2c < 4; ++w2c) {
        __syncthreads();
        // A stage: 16 kk x 64 h x 2 half-float4 (32B contiguous per (kk,h))
#pragma unroll
        for (int i = 0; i < 4; ++i) {
            int f = i * 512 + t;                       // 0..2047
            int half = f & 1, hh = (f >> 1) & 63, kk = f >> 7;
            float4 v = *(const float4*)(Ab + (long)(w2c * 16 + kk) * 4096 + hh * 64 + half * 4);
            *(float4*)&As[kk][hh][half * 4] = v;
        }
        // B stage: 16 kk x 8 w x 16 float4 (256B contiguous per (kk,w))
#pragma unroll
        for (int i = 0; i < 4; ++i) {
            int f = i * 512 + t;
            int d4 = f & 15, ww = (f >> 4) & 7, kk = f >> 7;
            float4 v = *(const float4*)(Bb + (long)(w2c * 16 + kk) * 4096 + ww * 64 + d4 * 4);
            *(float4*)&Bs[kk][ww][d4 * 4] = v;
        }
        __syncthreads();
        for (int kk = 0; kk < 16; ++kk) {
            float a = As[kk][h][w];
            const float* br = &Bs[kk][w][0];
#pragma unroll
            for (int i = 0; i < 16; ++i) {
                acc0[i] = fmaf(a, br[i], acc0[i]);
                acc1[i] = fmaf(a, br[16 + i], acc1[i]);
                acc2[i] = fmaf(a, br[32 + i], acc2[i]);
                acc3[i] = fmaf(a, br[48 + i], acc3[i]);
            }
        }
    }
    // store: F[bc][h][wt*8+w][d], 128B per thread (contiguous)
    __hip_bfloat16* Fp = F + (long)bc * HWD + (long)h * 4096 + (wt * 8 + w) * 64;
    float tmp[16];
#pragma unroll
    for (int i = 0; i < 16; ++i) tmp[i] = acc0[i];
    pack_row_bf16(Fp, tmp);
#pragma unroll
    for (int i = 0; i < 16; ++i) tmp[i] = acc1[i];
    pack_row_bf16(Fp + 16, tmp);
#pragma unroll
    for (int i = 0; i < 16; ++i) tmp[i] = acc2[i];
    pack_row_bf16(Fp + 32, tmp);
#pragma unroll
    for (int i = 0; i < 16; ++i) tmp[i] = acc3[i];
    pack_row_bf16(Fp + 48, tmp);
}

// ---------------- map v4 (MFMA): out[n][c] = gelu( sum_k P[n][k] Wb[k][c] + b_map[c] ) ----
// P[n][k<64] = bf16(x[n][k] * F[k][n]),  P[n][k>=64] = At[k-64][n].
__global__ __launch_bounds__(256, 4) void k_map(const float* __restrict__ x,
        const __hip_bfloat16* __restrict__ F, const __hip_bfloat16* __restrict__ At,
        const __hip_bfloat16* __restrict__ Wb, const float* __restrict__ b_map,
        float* __restrict__ out) {
    __shared__ float xs[16][257];             // 16448 B
    __shared__ __hip_bfloat16 fa[16][264];    //  8448 B, F or At chunk
    __shared__ short Pl[256][24];             // 12288 B, 16 k bf16 + 8 pad
    __shared__ short Wt[64][136];             // 17408 B, [c][k 128 + 8 pad]

    int t = threadIdx.x;
    long n0 = (long)blockIdx.x * 256;
    int b = (int)(n0 >> 18);
    long nn0 = n0 & (HWD - 1);
    const float* xblk = x + n0 * 64;
    const __hip_bfloat16* Fb = F + (long)b * 64 * HWD + nn0;
    const __hip_bfloat16* Ab = At + (long)b * 64 * HWD + nn0;

    // load W tile once: Wb[c][k] 64x128 bf16
#pragma unroll
    for (int i = 0; i < 4; ++i) {
        int e = i * 256 + t;                  // uint4 index, 1024 total
        int c = e >> 4, kk = (e & 15) * 8;
        *(uint4*)&Wt[c][kk] = *(const uint4*)((const short*)Wb + c * 128 + kk);
    }

    int lane = t & 63, wv = t >> 6;
    int lrow = lane & 31, lhalf = lane >> 5;
    f32x16 acc00 = {0}, acc01 = {0}, acc10 = {0}, acc11 = {0};

    for (int kc = 0; kc < 8; ++kc) {
        __syncthreads();   // prev chunk's Pl/xs/fa readers done; covers Wt load at kc=0
        if (kc < 4) {
            // stage x chunk: each 64B line fetched by one float4 instruction
#pragma unroll
            for (int i2 = 0; i2 < 4; ++i2) {
                int f = i2 * 256 + t;
                int nr = f >> 2, j4 = (f & 3) * 4;
                float4 v = *(const float4*)(xblk + nr * 64 + kc * 16 + j4);
                xs[j4 + 0][nr] = v.x;
                xs[j4 + 1][nr] = v.y;
                xs[j4 + 2][nr] = v.z;
                xs[j4 + 3][nr] = v.w;
            }
            // stage F chunk: 16 ch x 512B, uint4, fully coalesced
#pragma unroll
            for (int it = 0; it < 2; ++it) {
                int idx = it * 256 + t;
                int row = idx >> 5, seg = idx & 31;
                *(uint4*)&fa[row][seg * 8] =
                    *(const uint4*)(Fb + (long)(kc * 16 + row) * HWD + seg * 8);
            }
        } else {
            // stage At chunk
#pragma unroll
            for (int it = 0; it < 2; ++it) {
                int idx = it * 256 + t;
                int row = idx >> 5, seg = idx & 31;
                *(uint4*)&fa[row][seg * 8] =
                    *(const uint4*)(Ab + (long)((kc - 4) * 16 + row) * HWD + seg * 8);
            }
        }
        __syncthreads();
        // build P row t (16 bf16), write as 2x16B
        unsigned short pv[16];
        if (kc < 4) {
#pragma unroll
            for (int k2 = 0; k2 < 16; ++k2) {
                float p = xs[k2][t] * __bfloat162float(fa[k2][t]);
                pv[k2] = bfu(p);
            }
        } else {
#pragma unroll
            for (int k2 = 0; k2 < 16; ++k2)
                pv[k2] = *reinterpret_cast<const unsigned short*>(&fa[k2][t]);
        }
        *(uint4*)&Pl[t][0] = *(uint4*)&pv[0];
        *(uint4*)&Pl[t][8] = *(uint4*)&pv[8];
        __syncthreads();
        // MFMA K-step: A = P rows (n), B = Wt rows (c)
        bf16x8 a0 = *(const bf16x8*)&Pl[wv * 64 + lrow][lhalf * 8];
        bf16x8 a1 = *(const bf16x8*)&Pl[wv * 64 + 32 + lrow][lhalf * 8];
        bf16x8 b0 = *(const bf16x8*)&Wt[lrow][kc * 16 + lhalf * 8];
        bf16x8 b1 = *(const bf16x8*)&Wt[32 + lrow][kc * 16 + lhalf * 8];
        acc00 = __builtin_amdgcn_mfma_f32_32x32x16_bf16(a0, b0, acc00, 0, 0, 0);
        acc01 = __builtin_amdgcn_mfma_f32_32x32x16_bf16(a0, b1, acc01, 0, 0, 0);
        acc10 = __builtin_amdgcn_mfma_f32_32x32x16_bf16(a1, b0, acc10, 0, 0, 0);
        acc11 = __builtin_amdgcn_mfma_f32_32x32x16_bf16(a1, b1, acc11, 0, 0, 0);
    }

    // epilogue: bias + exact GELU + store.
    // D layout: col(c) = lane&31, row(n) = (reg&3)+8*(reg>>2)+4*lhalf
    float bs0 = b_map[lrow];
    float bs1 = b_map[32 + lrow];
    const float inv_sqrt2 = 0.70710678118654752440f;
    float* ob = out + (n0 + wv * 64) * 64;
#pragma unroll
    for (int reg = 0; reg < 16; ++reg) {
        int nrow = (reg & 3) + 8 * (reg >> 2) + 4 * lhalf;
        float v00 = acc00[reg] + bs0;
        float v01 = acc01[reg] + bs1;
        float v10 = acc10[reg] + bs0;
        float v11 = acc11[reg] + bs1;
        v00 = 0.5f * v00 * (1.f + erff(v00 * inv_sqrt2));
        v01 = 0.5f * v01 * (1.f + erff(v01 * inv_sqrt2));
        v10 = 0.5f * v10 * (1.f + erff(v10 * inv_sqrt2));
        v11 = 0.5f * v11 * (1.f + erff(v11 * inv_sqrt2));
        ob[(long)nrow * 64 + lrow] = v00;            // lanes 0-31 + 32-63: 2x128B contig
        ob[(long)nrow * 64 + 32 + lrow] = v01;
        ob[(long)(32 + nrow) * 64 + lrow] = v10;
        ob[(long)(32 + nrow) * 64 + 32 + lrow] = v11;
    }
}

extern "C" void kernel_launch(void* const* d_in, const int* in_sizes, int n_in,
                              void* d_out, int out_size, void* d_ws, size_t ws_size,
                              hipStream_t stream) {
    const float* x     = (const float*)d_in[0];
    const float* w_t   = (const float*)d_in[1];
    const float* b_t   = (const float*)d_in[2];
    const float* w_c   = (const float*)d_in[3];
    const float* b_c   = (const float*)d_in[4];
    const float* w_map = (const float*)d_in[5];
    const float* b_map = (const float*)d_in[6];
    float* out = (float*)d_out;
    float* ws = (float*)d_ws;

    // ws layout (float offsets), ~269 MB total:
    //  [0,        16777216)  Xc bf16  (33.5M elem)  -> reused as At bf16 after conv_c
    //  [16777216, 33554432)  Xt bf16                -> reused as F bf16 after conv_t
    //  [33554432, 67108864)  T fp32
    //  [67108864, ...)       A_t bf16 (147456) | A_c bf16 (147456) | Wb bf16 (8192)
    __hip_bfloat16* Xc = (__hip_bfloat16*)ws;
    __hip_bfloat16* Xt = (__hip_bfloat16*)(ws + 16777216L);
    float* T = ws + 33554432L;
    float* Cc = out;                                     // d_out as scratch
    __hip_bfloat16* A_t = (__hip_bfloat16*)(ws + 67108864L);
    __hip_bfloat16* A_c = (__hip_bfloat16*)(ws + 67182592L);
    __hip_bfloat16* Wb = (__hip_bfloat16*)(ws + 67256320L);
    __hip_bfloat16* At_bf = Xc;                          // 67 MB, Xc dead after convs
    __hip_bfloat16* F_bf = Xt;                           // 67 MB, Xt dead after convs

    hipLaunchKernelGGL(k_prep, dim3(576), dim3(256), 0, stream, w_t, w_c, w_map, A_t, A_c, Wb);
    hipLaunchKernelGGL(k_trans_c, dim3(1024, 2), dim3(256), 0, stream, x, Xc);
    hipLaunchKernelGGL(k_trans_t, dim3(1024, 2), dim3(256), 0, stream, x, Xt);
    hipLaunchKernelGGL(k_conv_mfma, dim3(1024), dim3(256), 0, stream, Xt, A_t, b_t, T);
    hipLaunchKernelGGL(k_conv_mfma, dim3(1024), dim3(256), 0, stream, Xc, A_c, b_c, Cc);
    hipLaunchKernelGGL(k_attn, dim3(8192), dim3(128), 0, stream, Cc, T, At_bf);
    hipLaunchKernelGGL(k_f, dim3(1024), dim3(512), 0, stream, Cc, T, F_bf);
    hipLaunchKernelGGL(k_map, dim3(2048), dim3(256), 0, stream, x, F_bf, At_bf, Wb, b_map, out);
}

// Round 9
// 780.906 us; speedup vs baseline: 1.3166x; 1.3166x over previous
//
#include <hip/hip_runtime.h>
#include <hip/hip_bf16.h>
#include <math.h>

#define HWD 262144   // 64*64*64

typedef __attribute__((ext_vector_type(8))) short bf16x8;   // 8 bf16 (4 VGPRs)
typedef __attribute__((ext_vector_type(16))) float f32x16;  // MFMA 32x32 accumulator

__device__ inline unsigned short bfu(float f) {
    __hip_bfloat16 h = __float2bfloat16(f);
    return *reinterpret_cast<unsigned short*>(&h);
}

// ---------------- prep: weights -> bf16 GEMM layout A[ks 72][oc 128][kk 16]; w_map -> Wb bf16 ----
// K order: k = ((g*3+r)*3+s)*64 + z,  ks=k>>4, kk=k&15.
__global__ void k_prep(const float* __restrict__ w_t, const float* __restrict__ w_c,
                       const float* __restrict__ w_map,
                       __hip_bfloat16* __restrict__ A_t, __hip_bfloat16* __restrict__ A_c,
                       __hip_bfloat16* __restrict__ Wb) {
    int i = blockIdx.x * 256 + threadIdx.x;
    if (i < 147456) {
        int kk = i & 15, oc = (i >> 4) & 127, ks = i >> 11;
        int z4 = ks & 3, kq = ks >> 2;          // kq = (g*3+r)*3+s in [0,18)
        int g = kq / 9, tap = kq - 9 * g;       // tap = r*3+s
        int z = z4 * 16 + kk;
        // w_t (128,2,64,3,3): ((o*2+g)*64+kh)*9 + tap,  z=kh
        A_t[i] = __float2bfloat16(w_t[((oc * 2 + g) * 64 + z) * 9 + tap]);
        // w_c (128,2,3,3,64): ((o*2+g)*9+tap)*64 + kd,  z=kd
        A_c[i] = __float2bfloat16(w_c[((oc * 2 + g) * 9 + tap) * 64 + z]);
    }
    if (i < 8192) {
        Wb[i] = __float2bfloat16(w_map[i]);   // w_map is (C,2C) row-major = [c][k]
    }
}

__device__ inline void pack_row_bf16(__hip_bfloat16* dst, const float* src) {
    unsigned short u[16];
#pragma unroll
    for (int j = 0; j < 16; ++j) u[j] = bfu(src[j]);
    uint4* q = reinterpret_cast<uint4*>(dst);
    q[0] = *reinterpret_cast<const uint4*>(&u[0]);
    q[1] = *reinterpret_cast<const uint4*>(&u[8]);
}

// ---------------- transpose x (B,N,C) -> Xc bf16, z4-plane layout [cg][z4][h*w][16] ------------
__global__ void k_trans_c(const float* __restrict__ x, __hip_bfloat16* __restrict__ Xc) {
    __shared__ unsigned short tile[256][68];
    int b = blockIdx.y;
    long n0 = (long)blockIdx.x * 256;
    int t = threadIdx.x;
    const float4* xp4 = (const float4*)(x + ((long)b * HWD + n0) * 64);
#pragma unroll
    for (int i = 0; i < 16; ++i) {
        int f4i = i * 256 + t;
        float4 v = xp4[f4i];
        int nl = f4i >> 4, c4 = (f4i & 15) * 4;
        ushort4 u;
        u.x = bfu(v.x); u.y = bfu(v.y); u.z = bfu(v.z); u.w = bfu(v.w);
        *(ushort4*)&tile[nl][c4] = u;
    }
    __syncthreads();
    int c = t >> 2, hwl = t & 3;
    int hw0 = blockIdx.x * 4;
    __hip_bfloat16* dst0 = Xc + (long)(b * 64 + c) * HWD + (long)(hw0 + hwl) * 16;
#pragma unroll
    for (int z4 = 0; z4 < 4; ++z4) {
        unsigned short u[16];
#pragma unroll
        for (int j = 0; j < 16; ++j) u[j] = tile[hwl * 64 + z4 * 16 + j][c];
        __hip_bfloat16* dst = dst0 + z4 * 65536;
        *(uint4*)dst = *(const uint4*)&u[0];
        *(uint4*)(dst + 8) = *(const uint4*)&u[8];
    }
}

// ---------------- transpose x -> Xt bf16, z4-plane layout [cg][z4][w*d][16] (inner 16 = h) -----
__global__ void k_trans_t(const float* __restrict__ x, __hip_bfloat16* __restrict__ Xt) {
    __shared__ unsigned short tile[256][68];   // [wdl*64+h][c]
    int b = blockIdx.y;
    int wd0 = blockIdx.x * 4;
    int t = threadIdx.x;
    const float* xb = x + (long)b * HWD * 64 + (long)wd0 * 64;
#pragma unroll
    for (int i = 0; i < 16; ++i) {
        int idx = i * 256 + t;              // float4 id over 64 h x 64 f
        int h = idx >> 6, f = idx & 63;     // per h: 4 wd x 64 c = 1KB contiguous
        float4 v = *(const float4*)(xb + (long)h * 262144 + f * 4);
        int wdl = f >> 4, c4 = (f & 15) * 4;
        ushort4 u;
        u.x = bfu(v.x); u.y = bfu(v.y); u.z = bfu(v.z); u.w = bfu(v.w);
        *(ushort4*)&tile[wdl * 64 + h][c4] = u;
    }
    __syncthreads();
    int c = t >> 2, wdl = t & 3;
    __hip_bfloat16* dst0 = Xt + (long)(b * 64 + c) * HWD + (long)(wd0 + wdl) * 16;
#pragma unroll
    for (int z4 = 0; z4 < 4; ++z4) {
        unsigned short u[16];
#pragma unroll
        for (int j = 0; j < 16; ++j) u[j] = tile[wdl * 64 + z4 * 16 + j][c];
        __hip_bfloat16* dst = dst0 + z4 * 65536;
        *(uint4*)dst = *(const uint4*)&u[0];
        *(uint4*)(dst + 8) = *(const uint4*)&u[8];
    }
}

// ---------------- unified MFMA conv v6: kq-granular LDS staging, 16 MFMAs/wave per barrier ----
// R8 lesson: acc ARRAYS spill to scratch (716MB writes) -> 4 NAMED accs only.
// R7/R4 lesson: the 22-24% wall = per-ks serial chain (4 MFMAs=128cyc vs ~400cyc load+sync).
// v6: stage ALL 4 z4-planes of B per iteration (16KB), double-buffered (32KB LDS),
// ONE barrier per kq (18 total), 16 MFMAs/wave (512 cyc) per interval >= load latency.
// A direct from global (L1-resident panel, R6-proven). launch_bounds(256,3): ~170-reg cap.
__global__ __launch_bounds__(256, 3) void k_conv_mfma(
        const __hip_bfloat16* __restrict__ X, const __hip_bfloat16* __restrict__ Aglob,
        const float* __restrict__ bias, float* __restrict__ Out) {
    int L = blockIdx.x;                       // 2048 = 64 grp * 32 pt
    int grp = (L & 7) * 8 + ((L >> 3) >> 5);  // XCD r handles grps [r*8, r*8+8)
    int pt = (L >> 3) & 31;
    int b = grp >> 5, ch = grp & 31;
    int p0 = pt * 2;
    const short* Xg = (const short*)(X + ((long)(b * 64 + 2 * ch)) * HWD);
    const short* Ag = (const short*)Aglob;
    int t = threadIdx.x;
    int lane = t & 63, wv = t >> 6;
    int O0 = (wv >> 1) * 64;              // wave oc base
    int N0 = (wv & 1) * 64;               // wave n base
    int lrow = lane & 31, lq = lane >> 5;

    // LDS: [buf][z4][khalf][128 rows x 8 shorts] = 32 KB
    __shared__ __align__(16) short Bsm[2][4][2][1024];

    f32x16 acc00 = {0}, acc01 = {0}, acc10 = {0}, acc11 = {0};

    // staging: thread covers (srow = t>>1 in [0,128), khalf = t&1), all 4 z4 planes.
    int srow = t >> 1, shalf = t & 1;
    int spr = srow >> 6, sq = srow & 63;  // (p-row, q) of the staged B-row
    const uint4 zero4 = {0u, 0u, 0u, 0u};
    uint4 ld0, ld1, ld2, ld3;             // named (no arrays -> no scratch)

    auto stage_load = [&](int kq) {
        int g = (kq >= 9) ? 1 : 0;
        int tap = kq - 9 * g;
        int r = tap / 3, s = tap - 3 * r;
        int pp = p0 + spr + r - 1, qq = sq + s - 1;
        bool ok = ((unsigned)pp < 64u) && ((unsigned)qq < 64u);
        const short* px = Xg + (long)g * HWD + (pp * 64 + qq) * 16 + shalf * 8;
        ld0 = ok ? *(const uint4*)(px)           : zero4;
        ld1 = ok ? *(const uint4*)(px + 65536)   : zero4;
        ld2 = ok ? *(const uint4*)(px + 131072)  : zero4;
        ld3 = ok ? *(const uint4*)(px + 196608)  : zero4;
    };
    auto stage_write = [&](int buf) {
        *(uint4*)&Bsm[buf][0][shalf][srow * 8] = ld0;
        *(uint4*)&Bsm[buf][1][shalf][srow * 8] = ld1;
        *(uint4*)&Bsm[buf][2][shalf][srow * 8] = ld2;
        *(uint4*)&Bsm[buf][3][shalf][srow * 8] = ld3;
    };

    stage_load(0);
    stage_write(0);
    __syncthreads();

    int buf = 0;
    for (int kq = 0; kq < 18; ++kq) {
        if (kq < 17) stage_load(kq + 1);       // in flight across the 16-MFMA cluster
#pragma unroll
        for (int z4 = 0; z4 < 4; ++z4) {
            int ks = kq * 4 + z4;
            const short* Apk = Ag + ks * 2048 + (O0 + lrow) * 16 + lq * 8;
            uint4 a0u = *(const uint4*)(Apk);
            uint4 a1u = *(const uint4*)(Apk + 512);
            bf16x8 a0 = *(bf16x8*)&a0u;
            bf16x8 a1 = *(bf16x8*)&a1u;
            bf16x8 b0 = *(const bf16x8*)&Bsm[buf][z4][lq][(N0 + lrow) * 8];
            bf16x8 b1 = *(const bf16x8*)&Bsm[buf][z4][lq][(N0 + 32 + lrow) * 8];
            acc00 = __builtin_amdgcn_mfma_f32_32x32x16_bf16(a0, b0, acc00, 0, 0, 0);
            acc01 = __builtin_amdgcn_mfma_f32_32x32x16_bf16(a0, b1, acc01, 0, 0, 0);
            acc10 = __builtin_amdgcn_mfma_f32_32x32x16_bf16(a1, b0, acc10, 0, 0, 0);
            acc11 = __builtin_amdgcn_mfma_f32_32x32x16_bf16(a1, b1, acc11, 0, 0, 0);
        }
        if (kq < 17) {
            stage_write(buf ^ 1);              // buf^1 unread this kq; barrier gates readers
            __syncthreads();
            buf ^= 1;
        }
    }

    // store: C/D layout col=lane&31, row=(reg&3)+8*(reg>>2)+4*(lane>>5)
    long base0 = ((long)(b * 64 + 2 * ch)) * HWD + (long)p0 * 64;
    int n0l = N0 + lrow, n1l = N0 + 32 + lrow;
    long noff0 = (long)(n0l >> 6) * 64 + (n0l & 63);
    long noff1 = (long)(n1l >> 6) * 64 + (n1l & 63);
#pragma unroll
    for (int reg = 0; reg < 16; ++reg) {
        int row = (reg & 3) + 8 * (reg >> 2) + 4 * lq;
        int oc0 = O0 + row, oc1 = O0 + 32 + row;
        long cb0 = base0 + (long)(oc0 >> 6) * HWD + (long)(oc0 & 63) * 4096;
        long cb1 = base0 + (long)(oc1 >> 6) * HWD + (long)(oc1 & 63) * 4096;
        float bs0 = bias[oc0], bs1 = bias[oc1];
        Out[cb0 + noff0] = acc00[reg] + bs0;
        Out[cb0 + noff1] = acc01[reg] + bs0;
        Out[cb1 + noff0] = acc10[reg] + bs1;
        Out[cb1 + noff1] = acc11[reg] + bs1;
    }
}

// ---------------- attn v2: At[b,c,h,w2,d] = sum_w Cc[b,c,w2,h,w] * T[b,c,w2,w,d] (bf16 out) ----
__global__ __launch_bounds__(128) void k_attn(const float* __restrict__ Cc,
        const float* __restrict__ T, __hip_bfloat16* __restrict__ At) {
    __shared__ float As[64][65];   // [h][w]
    __shared__ float Bs[64][64];   // [w][d]
    int bc = blockIdx.x >> 6, w2 = blockIdx.x & 63;
    const float4* Ap4 = (const float4*)(Cc + ((long)bc * 64 + w2) * 4096);
    const float4* Bp4 = (const float4*)(T + ((long)bc * 64 + w2) * 4096);
    int t = threadIdx.x;
#pragma unroll
    for (int i = 0; i < 8; ++i) {
        int f = i * 128 + t;               // float4 id, 1024 total
        int r = f >> 4, q4 = (f & 15) * 4;
        float4 v = Ap4[f];
        As[r][q4 + 0] = v.x; As[r][q4 + 1] = v.y; As[r][q4 + 2] = v.z; As[r][q4 + 3] = v.w;
        float4 w = Bp4[f];
        *(float4*)&Bs[r][q4] = w;
    }
    __syncthreads();
    int h2 = t >> 2, dg = (t & 3) * 16;
    f32x16 acc0 = {0}, acc1 = {0};
    for (int k = 0; k < 64; ++k) {
        float a0 = As[h2][k];
        float a1 = As[h2 + 32][k];
        const float* br = &Bs[k][dg];
#pragma unroll
        for (int i = 0; i < 16; ++i) {
            acc0[i] = fmaf(a0, br[i], acc0[i]);
            acc1[i] = fmaf(a1, br[i], acc1[i]);
        }
    }
    float tmp[16];
    __hip_bfloat16* Ab = At + (long)bc * HWD + (long)h2 * 4096 + w2 * 64 + dg;
#pragma unroll
    for (int i = 0; i < 16; ++i) tmp[i] = acc0[i];
    pack_row_bf16(Ab, tmp);
#pragma unroll
    for (int i = 0; i < 16; ++i) tmp[i] = acc1[i];
    pack_row_bf16(Ab + 32L * 4096, tmp);
}

// ---------------- f: F[b,c,h,w,d] = sum_w2 Cc[b,c,w2,h,w] * T[b,c,w2,w,d] (bf16 out) ----
__global__ __launch_bounds__(512, 4) void k_f(const float* __restrict__ Cc,
        const float* __restrict__ T, __hip_bfloat16* __restrict__ F) {
    __shared__ float As[16][64][8];   // [kk][h][w]        32 KB
    __shared__ float Bs[16][8][68];   // [kk][w][d(+pad)]  34 KB
    int L = blockIdx.x;               // 1024 = 128 bc * 8 wt
    int xcd = L & 7, j = L >> 3;      // j 0..127
    int bc = xcd * 16 + (j >> 3), wt = j & 7;
    const float* Ab = Cc + (long)bc * HWD + wt * 8;
    const float* Bb = T + (long)bc * HWD + wt * 8 * 64;
    int t = threadIdx.x;
    int w = t & 7, h = t >> 3;
    f32x16 acc0 = {0}, acc1 = {0}, acc2 = {0}, acc3 = {0};

    for (int w2c = 0; w2c < 4; ++w2c) {
        __syncthreads();
        // A stage: 16 kk x 64 h x 2 half-float4 (32B contiguous per (kk,h))
#pragma unroll
        for (int i = 0; i < 4; ++i) {
            int f = i * 512 + t;                       // 0..2047
            int half = f & 1, hh = (f >> 1) & 63, kk = f >> 7;
            float4 v = *(const float4*)(Ab + (long)(w2c * 16 + kk) * 4096 + hh * 64 + half * 4);
            *(float4*)&As[kk][hh][half * 4] = v;
        }
        // B stage: 16 kk x 8 w x 16 float4 (256B contiguous per (kk,w))
#pragma unroll
        for (int i = 0; i < 4; ++i) {
            int f = i * 512 + t;
            int d4 = f & 15, ww = (f >> 4) & 7, kk = f >> 7;
            float4 v = *(const float4*)(Bb + (long)(w2c * 16 + kk) * 4096 + ww * 64 + d4 * 4);
            *(float4*)&Bs[kk][ww][d4 * 4] = v;
        }
        __syncthreads();
        for (int kk = 0; kk < 16; ++kk) {
            float a = As[kk][h][w];
            const float* br = &Bs[kk][w][0];
#pragma unroll
            for (int i = 0; i < 16; ++i) {
                acc0[i] = fmaf(a, br[i], acc0[i]);
                acc1[i] = fmaf(a, br[16 + i], acc1[i]);
                acc2[i] = fmaf(a, br[32 + i], acc2[i]);
                acc3[i] = fmaf(a, br[48 + i], acc3[i]);
            }
        }
    }
    // store: F[bc][h][wt*8+w][d], 128B per thread (contiguous)
    __hip_bfloat16* Fp = F + (long)bc * HWD + (long)h * 4096 + (wt * 8 + w) * 64;
    float tmp[16];
#pragma unroll
    for (int i = 0; i < 16; ++i) tmp[i] = acc0[i];
    pack_row_bf16(Fp, tmp);
#pragma unroll
    for (int i = 0; i < 16; ++i) tmp[i] = acc1[i];
    pack_row_bf16(Fp + 16, tmp);
#pragma unroll
    for (int i = 0; i < 16; ++i) tmp[i] = acc2[i];
    pack_row_bf16(Fp + 32, tmp);
#pragma unroll
    for (int i = 0; i < 16; ++i) tmp[i] = acc3[i];
    pack_row_bf16(Fp + 48, tmp);
}

// ---------------- map v4 (MFMA): out[n][c] = gelu( sum_k P[n][k] Wb[k][c] + b_map[c] ) ----
// P[n][k<64] = bf16(x[n][k] * F[k][n]),  P[n][k>=64] = At[k-64][n].
__global__ __launch_bounds__(256, 4) void k_map(const float* __restrict__ x,
        const __hip_bfloat16* __restrict__ F, const __hip_bfloat16* __restrict__ At,
        const __hip_bfloat16* __restrict__ Wb, const float* __restrict__ b_map,
        float* __restrict__ out) {
    __shared__ float xs[16][257];             // 16448 B
    __shared__ __hip_bfloat16 fa[16][264];    //  8448 B, F or At chunk
    __shared__ short Pl[256][24];             // 12288 B, 16 k bf16 + 8 pad
    __shared__ short Wt[64][136];             // 17408 B, [c][k 128 + 8 pad]

    int t = threadIdx.x;
    long n0 = (long)blockIdx.x * 256;
    int b = (int)(n0 >> 18);
    long nn0 = n0 & (HWD - 1);
    const float* xblk = x + n0 * 64;
    const __hip_bfloat16* Fb = F + (long)b * 64 * HWD + nn0;
    const __hip_bfloat16* Ab = At + (long)b * 64 * HWD + nn0;

    // load W tile once: Wb[c][k] 64x128 bf16
#pragma unroll
    for (int i = 0; i < 4; ++i) {
        int e = i * 256 + t;                  // uint4 index, 1024 total
        int c = e >> 4, kk = (e & 15) * 8;
        *(uint4*)&Wt[c][kk] = *(const uint4*)((const short*)Wb + c * 128 + kk);
    }

    int lane = t & 63, wv = t >> 6;
    int lrow = lane & 31, lhalf = lane >> 5;
    f32x16 acc00 = {0}, acc01 = {0}, acc10 = {0}, acc11 = {0};

    for (int kc = 0; kc < 8; ++kc) {
        __syncthreads();   // prev chunk's Pl/xs/fa readers done; covers Wt load at kc=0
        if (kc < 4) {
            // stage x chunk: each 64B line fetched by one float4 instruction
#pragma unroll
            for (int i2 = 0; i2 < 4; ++i2) {
                int f = i2 * 256 + t;
                int nr = f >> 2, j4 = (f & 3) * 4;
                float4 v = *(const float4*)(xblk + nr * 64 + kc * 16 + j4);
                xs[j4 + 0][nr] = v.x;
                xs[j4 + 1][nr] = v.y;
                xs[j4 + 2][nr] = v.z;
                xs[j4 + 3][nr] = v.w;
            }
            // stage F chunk: 16 ch x 512B, uint4, fully coalesced
#pragma unroll
            for (int it = 0; it < 2; ++it) {
                int idx = it * 256 + t;
                int row = idx >> 5, seg = idx & 31;
                *(uint4*)&fa[row][seg * 8] =
                    *(const uint4*)(Fb + (long)(kc * 16 + row) * HWD + seg * 8);
            }
        } else {
            // stage At chunk
#pragma unroll
            for (int it = 0; it < 2; ++it) {
                int idx = it * 256 + t;
                int row = idx >> 5, seg = idx & 31;
                *(uint4*)&fa[row][seg * 8] =
                    *(const uint4*)(Ab + (long)((kc - 4) * 16 + row) * HWD + seg * 8);
            }
        }
        __syncthreads();
        // build P row t (16 bf16), write as 2x16B
        unsigned short pv[16];
        if (kc < 4) {
#pragma unroll
            for (int k2 = 0; k2 < 16; ++k2) {
                float p = xs[k2][t] * __bfloat162float(fa[k2][t]);
                pv[k2] = bfu(p);
            }
        } else {
#pragma unroll
            for (int k2 = 0; k2 < 16; ++k2)
                pv[k2] = *reinterpret_cast<const unsigned short*>(&fa[k2][t]);
        }
        *(uint4*)&Pl[t][0] = *(uint4*)&pv[0];
        *(uint4*)&Pl[t][8] = *(uint4*)&pv[8];
        __syncthreads();
        // MFMA K-step: A = P rows (n), B = Wt rows (c)
        bf16x8 a0 = *(const bf16x8*)&Pl[wv * 64 + lrow][lhalf * 8];
        bf16x8 a1 = *(const bf16x8*)&Pl[wv * 64 + 32 + lrow][lhalf * 8];
        bf16x8 b0 = *(const bf16x8*)&Wt[lrow][kc * 16 + lhalf * 8];
        bf16x8 b1 = *(const bf16x8*)&Wt[32 + lrow][kc * 16 + lhalf * 8];
        acc00 = __builtin_amdgcn_mfma_f32_32x32x16_bf16(a0, b0, acc00, 0, 0, 0);
        acc01 = __builtin_amdgcn_mfma_f32_32x32x16_bf16(a0, b1, acc01, 0, 0, 0);
        acc10 = __builtin_amdgcn_mfma_f32_32x32x16_bf16(a1, b0, acc10, 0, 0, 0);
        acc11 = __builtin_amdgcn_mfma_f32_32x32x16_bf16(a1, b1, acc11, 0, 0, 0);
    }

    // epilogue: bias + exact GELU + store.
    // D layout: col(c) = lane&31, row(n) = (reg&3)+8*(reg>>2)+4*lhalf
    float bs0 = b_map[lrow];
    float bs1 = b_map[32 + lrow];
    const float inv_sqrt2 = 0.70710678118654752440f;
    float* ob = out + (n0 + wv * 64) * 64;
#pragma unroll
    for (int reg = 0; reg < 16; ++reg) {
        int nrow = (reg & 3) + 8 * (reg >> 2) + 4 * lhalf;
        float v00 = acc00[reg] + bs0;
        float v01 = acc01[reg] + bs1;
        float v10 = acc10[reg] + bs0;
        float v11 = acc11[reg] + bs1;
        v00 = 0.5f * v00 * (1.f + erff(v00 * inv_sqrt2));
        v01 = 0.5f * v01 * (1.f + erff(v01 * inv_sqrt2));
        v10 = 0.5f * v10 * (1.f + erff(v10 * inv_sqrt2));
        v11 = 0.5f * v11 * (1.f + erff(v11 * inv_sqrt2));
        ob[(long)nrow * 64 + lrow] = v00;            // lanes 0-31 + 32-63: 2x128B contig
        ob[(long)nrow * 64 + 32 + lrow] = v01;
        ob[(long)(32 + nrow) * 64 + lrow] = v10;
        ob[(long)(32 + nrow) * 64 + 32 + lrow] = v11;
    }
}

extern "C" void kernel_launch(void* const* d_in, const int* in_sizes, int n_in,
                              void* d_out, int out_size, void* d_ws, size_t ws_size,
                              hipStream_t stream) {
    const float* x     = (const float*)d_in[0];
    const float* w_t   = (const float*)d_in[1];
    const float* b_t   = (const float*)d_in[2];
    const float* w_c   = (const float*)d_in[3];
    const float* b_c   = (const float*)d_in[4];
    const float* w_map = (const float*)d_in[5];
    const float* b_map = (const float*)d_in[6];
    float* out = (float*)d_out;
    float* ws = (float*)d_ws;

    // ws layout (float offsets), ~269 MB total:
    //  [0,        16777216)  Xc bf16  (33.5M elem)  -> reused as At bf16 after conv_c
    //  [16777216, 33554432)  Xt bf16                -> reused as F bf16 after conv_t
    //  [33554432, 67108864)  T fp32
    //  [67108864, ...)       A_t bf16 (147456) | A_c bf16 (147456) | Wb bf16 (8192)
    __hip_bfloat16* Xc = (__hip_bfloat16*)ws;
    __hip_bfloat16* Xt = (__hip_bfloat16*)(ws + 16777216L);
    float* T = ws + 33554432L;
    float* Cc = out;                                     // d_out as scratch
    __hip_bfloat16* A_t = (__hip_bfloat16*)(ws + 67108864L);
    __hip_bfloat16* A_c = (__hip_bfloat16*)(ws + 67182592L);
    __hip_bfloat16* Wb = (__hip_bfloat16*)(ws + 67256320L);
    __hip_bfloat16* At_bf = Xc;                          // 67 MB, Xc dead after convs
    __hip_bfloat16* F_bf = Xt;                           // 67 MB, Xt dead after convs

    hipLaunchKernelGGL(k_prep, dim3(576), dim3(256), 0, stream, w_t, w_c, w_map, A_t, A_c, Wb);
    hipLaunchKernelGGL(k_trans_c, dim3(1024, 2), dim3(256), 0, stream, x, Xc);
    hipLaunchKernelGGL(k_trans_t, dim3(1024, 2), dim3(256), 0, stream, x, Xt);
    hipLaunchKernelGGL(k_conv_mfma, dim3(2048), dim3(256), 0, stream, Xt, A_t, b_t, T);
    hipLaunchKernelGGL(k_conv_mfma, dim3(2048), dim3(256), 0, stream, Xc, A_c, b_c, Cc);
    hipLaunchKernelGGL(k_attn, dim3(8192), dim3(128), 0, stream, Cc, T, At_bf);
    hipLaunchKernelGGL(k_f, dim3(1024), dim3(512), 0, stream, Cc, T, F_bf);
    hipLaunchKernelGGL(k_map, dim3(2048), dim3(256), 0, stream, x, F_bf, At_bf, Wb, b_map, out);
}

// Round 10
// 762.646 us; speedup vs baseline: 1.3482x; 1.0239x over previous
//
#include <hip/hip_runtime.h>
#include <hip/hip_bf16.h>
#include <math.h>

#define HWD 262144   // 64*64*64

typedef __attribute__((ext_vector_type(8))) short bf16x8;   // 8 bf16 (4 VGPRs)
typedef __attribute__((ext_vector_type(16))) float f32x16;  // MFMA 32x32 accumulator

__device__ inline unsigned short bfu(float f) {
    __hip_bfloat16 h = __float2bfloat16(f);
    return *reinterpret_cast<unsigned short*>(&h);
}

// ---------------- prep: weights -> bf16 GEMM layout A[ks 72][oc 128][kk 16]; w_map -> Wb bf16 ----
// K order: k = ((g*3+r)*3+s)*64 + z,  ks=k>>4, kk=k&15.
__global__ void k_prep(const float* __restrict__ w_t, const float* __restrict__ w_c,
                       const float* __restrict__ w_map,
                       __hip_bfloat16* __restrict__ A_t, __hip_bfloat16* __restrict__ A_c,
                       __hip_bfloat16* __restrict__ Wb) {
    int i = blockIdx.x * 256 + threadIdx.x;
    if (i < 147456) {
        int kk = i & 15, oc = (i >> 4) & 127, ks = i >> 11;
        int z4 = ks & 3, kq = ks >> 2;          // kq = (g*3+r)*3+s in [0,18)
        int g = kq / 9, tap = kq - 9 * g;       // tap = r*3+s
        int z = z4 * 16 + kk;
        // w_t (128,2,64,3,3): ((o*2+g)*64+kh)*9 + tap,  z=kh
        A_t[i] = __float2bfloat16(w_t[((oc * 2 + g) * 64 + z) * 9 + tap]);
        // w_c (128,2,3,3,64): ((o*2+g)*9+tap)*64 + kd,  z=kd
        A_c[i] = __float2bfloat16(w_c[((oc * 2 + g) * 9 + tap) * 64 + z]);
    }
    if (i < 8192) {
        Wb[i] = __float2bfloat16(w_map[i]);   // w_map is (C,2C) row-major = [c][k]
    }
}

__device__ inline void pack_row_bf16(__hip_bfloat16* dst, const float* src) {
    unsigned short u[16];
#pragma unroll
    for (int j = 0; j < 16; ++j) u[j] = bfu(src[j]);
    uint4* q = reinterpret_cast<uint4*>(dst);
    q[0] = *reinterpret_cast<const uint4*>(&u[0]);
    q[1] = *reinterpret_cast<const uint4*>(&u[8]);
}

// ---------------- transpose x (B,N,C) -> Xc bf16, z4-plane layout [cg][z4][h*w][16] ------------
__global__ void k_trans_c(const float* __restrict__ x, __hip_bfloat16* __restrict__ Xc) {
    __shared__ unsigned short tile[256][68];
    int b = blockIdx.y;
    long n0 = (long)blockIdx.x * 256;
    int t = threadIdx.x;
    const float4* xp4 = (const float4*)(x + ((long)b * HWD + n0) * 64);
#pragma unroll
    for (int i = 0; i < 16; ++i) {
        int f4i = i * 256 + t;
        float4 v = xp4[f4i];
        int nl = f4i >> 4, c4 = (f4i & 15) * 4;
        ushort4 u;
        u.x = bfu(v.x); u.y = bfu(v.y); u.z = bfu(v.z); u.w = bfu(v.w);
        *(ushort4*)&tile[nl][c4] = u;
    }
    __syncthreads();
    int c = t >> 2, hwl = t & 3;
    int hw0 = blockIdx.x * 4;
    __hip_bfloat16* dst0 = Xc + (long)(b * 64 + c) * HWD + (long)(hw0 + hwl) * 16;
#pragma unroll
    for (int z4 = 0; z4 < 4; ++z4) {
        unsigned short u[16];
#pragma unroll
        for (int j = 0; j < 16; ++j) u[j] = tile[hwl * 64 + z4 * 16 + j][c];
        __hip_bfloat16* dst = dst0 + z4 * 65536;
        *(uint4*)dst = *(const uint4*)&u[0];
        *(uint4*)(dst + 8) = *(const uint4*)&u[8];
    }
}

// ---------------- transpose x -> Xt bf16, z4-plane layout [cg][z4][w*d][16] (inner 16 = h) -----
__global__ void k_trans_t(const float* __restrict__ x, __hip_bfloat16* __restrict__ Xt) {
    __shared__ unsigned short tile[256][68];   // [wdl*64+h][c]
    int b = blockIdx.y;
    int wd0 = blockIdx.x * 4;
    int t = threadIdx.x;
    const float* xb = x + (long)b * HWD * 64 + (long)wd0 * 64;
#pragma unroll
    for (int i = 0; i < 16; ++i) {
        int idx = i * 256 + t;              // float4 id over 64 h x 64 f
        int h = idx >> 6, f = idx & 63;     // per h: 4 wd x 64 c = 1KB contiguous
        float4 v = *(const float4*)(xb + (long)h * 262144 + f * 4);
        int wdl = f >> 4, c4 = (f & 15) * 4;
        ushort4 u;
        u.x = bfu(v.x); u.y = bfu(v.y); u.z = bfu(v.z); u.w = bfu(v.w);
        *(ushort4*)&tile[wdl * 64 + h][c4] = u;
    }
    __syncthreads();
    int c = t >> 2, wdl = t & 3;
    __hip_bfloat16* dst0 = Xt + (long)(b * 64 + c) * HWD + (long)(wd0 + wdl) * 16;
#pragma unroll
    for (int z4 = 0; z4 < 4; ++z4) {
        unsigned short u[16];
#pragma unroll
        for (int j = 0; j < 16; ++j) u[j] = tile[wdl * 64 + z4 * 16 + j][c];
        __hip_bfloat16* dst = dst0 + z4 * 65536;
        *(uint4*)dst = *(const uint4*)&u[0];
        *(uint4*)(dst + 8) = *(const uint4*)&u[8];
    }
}

// ---------------- unified MFMA conv v6: kq-granular LDS staging, 16 MFMAs/wave per barrier ----
// (R9-benched: conv out of top-5.)
__global__ __launch_bounds__(256, 3) void k_conv_mfma(
        const __hip_bfloat16* __restrict__ X, const __hip_bfloat16* __restrict__ Aglob,
        const float* __restrict__ bias, float* __restrict__ Out) {
    int L = blockIdx.x;                       // 2048 = 64 grp * 32 pt
    int grp = (L & 7) * 8 + ((L >> 3) >> 5);  // XCD r handles grps [r*8, r*8+8)
    int pt = (L >> 3) & 31;
    int b = grp >> 5, ch = grp & 31;
    int p0 = pt * 2;
    const short* Xg = (const short*)(X + ((long)(b * 64 + 2 * ch)) * HWD);
    const short* Ag = (const short*)Aglob;
    int t = threadIdx.x;
    int lane = t & 63, wv = t >> 6;
    int O0 = (wv >> 1) * 64;              // wave oc base
    int N0 = (wv & 1) * 64;               // wave n base
    int lrow = lane & 31, lq = lane >> 5;

    // LDS: [buf][z4][khalf][128 rows x 8 shorts] = 32 KB
    __shared__ __align__(16) short Bsm[2][4][2][1024];

    f32x16 acc00 = {0}, acc01 = {0}, acc10 = {0}, acc11 = {0};

    int srow = t >> 1, shalf = t & 1;
    int spr = srow >> 6, sq = srow & 63;  // (p-row, q) of the staged B-row
    const uint4 zero4 = {0u, 0u, 0u, 0u};
    uint4 ld0, ld1, ld2, ld3;             // named (no arrays -> no scratch)

    auto stage_load = [&](int kq) {
        int g = (kq >= 9) ? 1 : 0;
        int tap = kq - 9 * g;
        int r = tap / 3, s = tap - 3 * r;
        int pp = p0 + spr + r - 1, qq = sq + s - 1;
        bool ok = ((unsigned)pp < 64u) && ((unsigned)qq < 64u);
        const short* px = Xg + (long)g * HWD + (pp * 64 + qq) * 16 + shalf * 8;
        ld0 = ok ? *(const uint4*)(px)           : zero4;
        ld1 = ok ? *(const uint4*)(px + 65536)   : zero4;
        ld2 = ok ? *(const uint4*)(px + 131072)  : zero4;
        ld3 = ok ? *(const uint4*)(px + 196608)  : zero4;
    };
    auto stage_write = [&](int buf) {
        *(uint4*)&Bsm[buf][0][shalf][srow * 8] = ld0;
        *(uint4*)&Bsm[buf][1][shalf][srow * 8] = ld1;
        *(uint4*)&Bsm[buf][2][shalf][srow * 8] = ld2;
        *(uint4*)&Bsm[buf][3][shalf][srow * 8] = ld3;
    };

    stage_load(0);
    stage_write(0);
    __syncthreads();

    int buf = 0;
    for (int kq = 0; kq < 18; ++kq) {
        if (kq < 17) stage_load(kq + 1);       // in flight across the 16-MFMA cluster
#pragma unroll
        for (int z4 = 0; z4 < 4; ++z4) {
            int ks = kq * 4 + z4;
            const short* Apk = Ag + ks * 2048 + (O0 + lrow) * 16 + lq * 8;
            uint4 a0u = *(const uint4*)(Apk);
            uint4 a1u = *(const uint4*)(Apk + 512);
            bf16x8 a0 = *(bf16x8*)&a0u;
            bf16x8 a1 = *(bf16x8*)&a1u;
            bf16x8 b0 = *(const bf16x8*)&Bsm[buf][z4][lq][(N0 + lrow) * 8];
            bf16x8 b1 = *(const bf16x8*)&Bsm[buf][z4][lq][(N0 + 32 + lrow) * 8];
            acc00 = __builtin_amdgcn_mfma_f32_32x32x16_bf16(a0, b0, acc00, 0, 0, 0);
            acc01 = __builtin_amdgcn_mfma_f32_32x32x16_bf16(a0, b1, acc01, 0, 0, 0);
            acc10 = __builtin_amdgcn_mfma_f32_32x32x16_bf16(a1, b0, acc10, 0, 0, 0);
            acc11 = __builtin_amdgcn_mfma_f32_32x32x16_bf16(a1, b1, acc11, 0, 0, 0);
        }
        if (kq < 17) {
            stage_write(buf ^ 1);
            __syncthreads();
            buf ^= 1;
        }
    }

    // store: C/D layout col=lane&31, row=(reg&3)+8*(reg>>2)+4*(lane>>5)
    long base0 = ((long)(b * 64 + 2 * ch)) * HWD + (long)p0 * 64;
    int n0l = N0 + lrow, n1l = N0 + 32 + lrow;
    long noff0 = (long)(n0l >> 6) * 64 + (n0l & 63);
    long noff1 = (long)(n1l >> 6) * 64 + (n1l & 63);
#pragma unroll
    for (int reg = 0; reg < 16; ++reg) {
        int row = (reg & 3) + 8 * (reg >> 2) + 4 * lq;
        int oc0 = O0 + row, oc1 = O0 + 32 + row;
        long cb0 = base0 + (long)(oc0 >> 6) * HWD + (long)(oc0 & 63) * 4096;
        long cb1 = base0 + (long)(oc1 >> 6) * HWD + (long)(oc1 & 63) * 4096;
        float bs0 = bias[oc0], bs1 = bias[oc1];
        Out[cb0 + noff0] = acc00[reg] + bs0;
        Out[cb0 + noff1] = acc01[reg] + bs0;
        Out[cb1 + noff0] = acc10[reg] + bs1;
        Out[cb1 + noff1] = acc11[reg] + bs1;
    }
}

// ---------------- attn v2: At[b,c,h,w2,d] = sum_w Cc[b,c,w2,h,w] * T[b,c,w2,w,d] (bf16 out) ----
__global__ __launch_bounds__(128) void k_attn(const float* __restrict__ Cc,
        const float* __restrict__ T, __hip_bfloat16* __restrict__ At) {
    __shared__ float As[64][65];   // [h][w]
    __shared__ float Bs[64][64];   // [w][d]
    int bc = blockIdx.x >> 6, w2 = blockIdx.x & 63;
    const float4* Ap4 = (const float4*)(Cc + ((long)bc * 64 + w2) * 4096);
    const float4* Bp4 = (const float4*)(T + ((long)bc * 64 + w2) * 4096);
    int t = threadIdx.x;
#pragma unroll
    for (int i = 0; i < 8; ++i) {
        int f = i * 128 + t;               // float4 id, 1024 total
        int r = f >> 4, q4 = (f & 15) * 4;
        float4 v = Ap4[f];
        As[r][q4 + 0] = v.x; As[r][q4 + 1] = v.y; As[r][q4 + 2] = v.z; As[r][q4 + 3] = v.w;
        float4 w = Bp4[f];
        *(float4*)&Bs[r][q4] = w;
    }
    __syncthreads();
    int h2 = t >> 2, dg = (t & 3) * 16;
    f32x16 acc0 = {0}, acc1 = {0};
    for (int k = 0; k < 64; ++k) {
        float a0 = As[h2][k];
        float a1 = As[h2 + 32][k];
        const float* br = &Bs[k][dg];
#pragma unroll
        for (int i = 0; i < 16; ++i) {
            acc0[i] = fmaf(a0, br[i], acc0[i]);
            acc1[i] = fmaf(a1, br[i], acc1[i]);
        }
    }
    float tmp[16];
    __hip_bfloat16* Ab = At + (long)bc * HWD + (long)h2 * 4096 + w2 * 64 + dg;
#pragma unroll
    for (int i = 0; i < 16; ++i) tmp[i] = acc0[i];
    pack_row_bf16(Ab, tmp);
#pragma unroll
    for (int i = 0; i < 16; ++i) tmp[i] = acc1[i];
    pack_row_bf16(Ab + 32L * 4096, tmp);
}

// ---------------- f v3: F[b,c,h,w,d] = sum_w2 Cc[b,c,w2,h,w] * T[b,c,w2,w,d] (bf16 out) ----
// R9 diagnosis: v2 was LDS-pipe-bound (16 ds_read_b128 of Bs per 64 FMAs; 8192 b128/block
// x 8cyc x 4 blocks/CU = 109us ~ measured 125). v3: 256 threads, thread owns TWO h rows
// (h2, h2+32) with 8 NAMED f32x16 accs -> same Bs read feeds 128 FMAs, LDS traffic halved.
__global__ __launch_bounds__(256, 2) void k_f(const float* __restrict__ Cc,
        const float* __restrict__ T, __hip_bfloat16* __restrict__ F) {
    __shared__ float As[16][64][8];   // [kk][h][w]        32 KB
    __shared__ float Bs[16][8][68];   // [kk][w][d(+pad)]  34 KB
    int L = blockIdx.x;               // 1024 = 128 bc * 8 wt
    int xcd = L & 7, j = L >> 3;      // j 0..127
    int bc = xcd * 16 + (j >> 3), wt = j & 7;
    const float* Ab = Cc + (long)bc * HWD + wt * 8;
    const float* Bb = T + (long)bc * HWD + wt * 8 * 64;
    int t = threadIdx.x;
    int w = t & 7, h2 = t >> 3;       // h2 in 0..31
    f32x16 p00 = {0}, p01 = {0}, p02 = {0}, p03 = {0};
    f32x16 p10 = {0}, p11 = {0}, p12 = {0}, p13 = {0};

    for (int w2c = 0; w2c < 4; ++w2c) {
        __syncthreads();
        // A stage: 16 kk x 64 h x 2 half-float4 (32B contiguous per (kk,h))
#pragma unroll
        for (int i = 0; i < 8; ++i) {
            int f = i * 256 + t;                       // 0..2047
            int half = f & 1, hh = (f >> 1) & 63, kk = f >> 7;
            float4 v = *(const float4*)(Ab + (long)(w2c * 16 + kk) * 4096 + hh * 64 + half * 4);
            *(float4*)&As[kk][hh][half * 4] = v;
        }
        // B stage: 16 kk x 8 w x 16 float4 (256B contiguous per (kk,w))
#pragma unroll
        for (int i = 0; i < 8; ++i) {
            int f = i * 256 + t;
            int d4 = f & 15, ww = (f >> 4) & 7, kk = f >> 7;
            float4 v = *(const float4*)(Bb + (long)(w2c * 16 + kk) * 4096 + ww * 64 + d4 * 4);
            *(float4*)&Bs[kk][ww][d4 * 4] = v;
        }
        __syncthreads();
        for (int kk = 0; kk < 16; ++kk) {
            float a0 = As[kk][h2][w];
            float a1 = As[kk][h2 + 32][w];
            const float* br = &Bs[kk][w][0];
#pragma unroll
            for (int i = 0; i < 16; ++i) {
                p00[i] = fmaf(a0, br[i], p00[i]);
                p01[i] = fmaf(a0, br[16 + i], p01[i]);
                p02[i] = fmaf(a0, br[32 + i], p02[i]);
                p03[i] = fmaf(a0, br[48 + i], p03[i]);
                p10[i] = fmaf(a1, br[i], p10[i]);
                p11[i] = fmaf(a1, br[16 + i], p11[i]);
                p12[i] = fmaf(a1, br[32 + i], p12[i]);
                p13[i] = fmaf(a1, br[48 + i], p13[i]);
            }
        }
    }
    // store: F[bc][h][wt*8+w][d], 128B per h-row (contiguous)
    __hip_bfloat16* Fp = F + (long)bc * HWD + (long)h2 * 4096 + (wt * 8 + w) * 64;
    float tmp[16];
#pragma unroll
    for (int i = 0; i < 16; ++i) tmp[i] = p00[i];
    pack_row_bf16(Fp, tmp);
#pragma unroll
    for (int i = 0; i < 16; ++i) tmp[i] = p01[i];
    pack_row_bf16(Fp + 16, tmp);
#pragma unroll
    for (int i = 0; i < 16; ++i) tmp[i] = p02[i];
    pack_row_bf16(Fp + 32, tmp);
#pragma unroll
    for (int i = 0; i < 16; ++i) tmp[i] = p03[i];
    pack_row_bf16(Fp + 48, tmp);
    __hip_bfloat16* Fq = Fp + 32L * 4096;
#pragma unroll
    for (int i = 0; i < 16; ++i) tmp[i] = p10[i];
    pack_row_bf16(Fq, tmp);
#pragma unroll
    for (int i = 0; i < 16; ++i) tmp[i] = p11[i];
    pack_row_bf16(Fq + 16, tmp);
#pragma unroll
    for (int i = 0; i < 16; ++i) tmp[i] = p12[i];
    pack_row_bf16(Fq + 32, tmp);
#pragma unroll
    for (int i = 0; i < 16; ++i) tmp[i] = p13[i];
    pack_row_bf16(Fq + 48, tmp);
}

// ---------------- map v5 (MFMA): out[n][c] = gelu( sum_k P[n][k] Wb[k][c] + b_map[c] ) ----
// P[n][k<64] = bf16(x[n][k] * F[k][n]),  P[n][k>=64] = At[k-64][n].
// v5 vs v4: (a) Pl LDS round-trip DELETED — the MFMA A-frag distribution (lane l<32: own
// P k[0:8]; lane l>=32: lane(l-32)'s k[8:16]) is built with 8 intra-wave __shfl + selects,
// no barrier (each wave's 64 A-rows are its own 64 threads). (b) W fragments preloaded
// into registers (16 bf16x8, one-time) — Wt LDS + its 8-way bank conflicts deleted.
// LDS 54.7 -> 24.9 KB; barriers 24 -> 16/block.
__global__ __launch_bounds__(256, 2) void k_map(const float* __restrict__ x,
        const __hip_bfloat16* __restrict__ F, const __hip_bfloat16* __restrict__ At,
        const __hip_bfloat16* __restrict__ Wb, const float* __restrict__ b_map,
        float* __restrict__ out) {
    __shared__ float xs[16][257];             // 16448 B
    __shared__ __hip_bfloat16 fa[16][264];    //  8448 B, F or At chunk

    int t = threadIdx.x;
    long n0 = (long)blockIdx.x * 256;
    int b = (int)(n0 >> 18);
    long nn0 = n0 & (HWD - 1);
    const float* xblk = x + n0 * 64;
    const __hip_bfloat16* Fb = F + (long)b * 64 * HWD + nn0;
    const __hip_bfloat16* Ab = At + (long)b * 64 * HWD + nn0;

    int lane = t & 63, wv = t >> 6;
    int lrow = lane & 31, lhalf = lane >> 5;

    // preload W fragments: B-operand frag for ks=kc is W[c][kc*16 + lhalf*8 ..+8]
    const short* Wp = (const short*)Wb;
    bf16x8 wb0[8], wb1[8];                    // static-indexed in unrolled loop only
#pragma unroll
    for (int kc = 0; kc < 8; ++kc) {
        uint4 u0 = *(const uint4*)(Wp + lrow * 128 + kc * 16 + lhalf * 8);
        uint4 u1 = *(const uint4*)(Wp + (32 + lrow) * 128 + kc * 16 + lhalf * 8);
        wb0[kc] = *(bf16x8*)&u0;
        wb1[kc] = *(bf16x8*)&u1;
    }

    f32x16 acc00 = {0}, acc01 = {0}, acc10 = {0}, acc11 = {0};

#pragma unroll
    for (int kc = 0; kc < 8; ++kc) {
        __syncthreads();   // prev chunk's xs/fa readers done
        if (kc < 4) {
            // stage x chunk: each 64B line fetched by one float4 instruction
#pragma unroll
            for (int i2 = 0; i2 < 4; ++i2) {
                int f = i2 * 256 + t;
                int nr = f >> 2, j4 = (f & 3) * 4;
                float4 v = *(const float4*)(xblk + nr * 64 + kc * 16 + j4);
                xs[j4 + 0][nr] = v.x;
                xs[j4 + 1][nr] = v.y;
                xs[j4 + 2][nr] = v.z;
                xs[j4 + 3][nr] = v.w;
            }
            // stage F chunk: 16 ch x 512B, uint4, fully coalesced
#pragma unroll
            for (int it = 0; it < 2; ++it) {
                int idx = it * 256 + t;
                int row = idx >> 5, seg = idx & 31;
                *(uint4*)&fa[row][seg * 8] =
                    *(const uint4*)(Fb + (long)(kc * 16 + row) * HWD + seg * 8);
            }
        } else {
            // stage At chunk
#pragma unroll
            for (int it = 0; it < 2; ++it) {
                int idx = it * 256 + t;
                int row = idx >> 5, seg = idx & 31;
                *(uint4*)&fa[row][seg * 8] =
                    *(const uint4*)(Ab + (long)((kc - 4) * 16 + row) * HWD + seg * 8);
            }
        }
        __syncthreads();
        // build P row t (16 bf16) in registers
        unsigned short pv[16];
        if (kc < 4) {
#pragma unroll
            for (int k2 = 0; k2 < 16; ++k2) {
                float p = xs[k2][t] * __bfloat162float(fa[k2][t]);
                pv[k2] = bfu(p);
            }
        } else {
#pragma unroll
            for (int k2 = 0; k2 < 16; ++k2)
                pv[k2] = *reinterpret_cast<const unsigned short*>(&fa[k2][t]);
        }
        unsigned lo0 = (unsigned)pv[0]  | ((unsigned)pv[1]  << 16);
        unsigned lo1 = (unsigned)pv[2]  | ((unsigned)pv[3]  << 16);
        unsigned lo2 = (unsigned)pv[4]  | ((unsigned)pv[5]  << 16);
        unsigned lo3 = (unsigned)pv[6]  | ((unsigned)pv[7]  << 16);
        unsigned hi0 = (unsigned)pv[8]  | ((unsigned)pv[9]  << 16);
        unsigned hi1 = (unsigned)pv[10] | ((unsigned)pv[11] << 16);
        unsigned hi2 = (unsigned)pv[12] | ((unsigned)pv[13] << 16);
        unsigned hi3 = (unsigned)pv[14] | ((unsigned)pv[15] << 16);
        // A-frag assembly via intra-wave shuffles (no LDS, no barrier):
        // a0 rows 0-31:  l<32 -> own lo ; l>=32 -> hi of lane l-32
        // a1 rows 32-63: l<32 -> lo of lane l+32 ; l>=32 -> own hi
        int sl0 = lane & 31, sl1 = lane | 32;
        bool lowh = lane < 32;
        unsigned s00 = __shfl(hi0, sl0), s01 = __shfl(hi1, sl0);
        unsigned s02 = __shfl(hi2, sl0), s03 = __shfl(hi3, sl0);
        unsigned r00 = __shfl(lo0, sl1), r01 = __shfl(lo1, sl1);
        unsigned r02 = __shfl(lo2, sl1), r03 = __shfl(lo3, sl1);
        uint4 ua0, ua1;
        ua0.x = lowh ? lo0 : s00; ua0.y = lowh ? lo1 : s01;
        ua0.z = lowh ? lo2 : s02; ua0.w = lowh ? lo3 : s03;
        ua1.x = lowh ? r00 : hi0; ua1.y = lowh ? r01 : hi1;
        ua1.z = lowh ? r02 : hi2; ua1.w = lowh ? r03 : hi3;
        bf16x8 a0 = *(bf16x8*)&ua0;
        bf16x8 a1 = *(bf16x8*)&ua1;
        acc00 = __builtin_amdgcn_mfma_f32_32x32x16_bf16(a0, wb0[kc], acc00, 0, 0, 0);
        acc01 = __builtin_amdgcn_mfma_f32_32x32x16_bf16(a0, wb1[kc], acc01, 0, 0, 0);
        acc10 = __builtin_amdgcn_mfma_f32_32x32x16_bf16(a1, wb0[kc], acc10, 0, 0, 0);
        acc11 = __builtin_amdgcn_mfma_f32_32x32x16_bf16(a1, wb1[kc], acc11, 0, 0, 0);
    }

    // epilogue: bias + exact GELU + store.
    // D layout: col(c) = lane&31, row(n) = (reg&3)+8*(reg>>2)+4*lhalf
    float bs0 = b_map[lrow];
    float bs1 = b_map[32 + lrow];
    const float inv_sqrt2 = 0.70710678118654752440f;
    float* ob = out + (n0 + wv * 64) * 64;
#pragma unroll
    for (int reg = 0; reg < 16; ++reg) {
        int nrow = (reg & 3) + 8 * (reg >> 2) + 4 * lhalf;
        float v00 = acc00[reg] + bs0;
        float v01 = acc01[reg] + bs1;
        float v10 = acc10[reg] + bs0;
        float v11 = acc11[reg] + bs1;
        v00 = 0.5f * v00 * (1.f + erff(v00 * inv_sqrt2));
        v01 = 0.5f * v01 * (1.f + erff(v01 * inv_sqrt2));
        v10 = 0.5f * v10 * (1.f + erff(v10 * inv_sqrt2));
        v11 = 0.5f * v11 * (1.f + erff(v11 * inv_sqrt2));
        ob[(long)nrow * 64 + lrow] = v00;            // lanes 0-31 + 32-63: 2x128B contig
        ob[(long)nrow * 64 + 32 + lrow] = v01;
        ob[(long)(32 + nrow) * 64 + lrow] = v10;
        ob[(long)(32 + nrow) * 64 + 32 + lrow] = v11;
    }
}

extern "C" void kernel_launch(void* const* d_in, const int* in_sizes, int n_in,
                              void* d_out, int out_size, void* d_ws, size_t ws_size,
                              hipStream_t stream) {
    const float* x     = (const float*)d_in[0];
    const float* w_t   = (const float*)d_in[1];
    const float* b_t   = (const float*)d_in[2];
    const float* w_c   = (const float*)d_in[3];
    const float* b_c   = (const float*)d_in[4];
    const float* w_map = (const float*)d_in[5];
    const float* b_map = (const float*)d_in[6];
    float* out = (float*)d_out;
    float* ws = (float*)d_ws;

    // ws layout (float offsets), ~269 MB total:
    //  [0,        16777216)  Xc bf16  (33.5M elem)  -> reused as At bf16 after conv_c
    //  [16777216, 33554432)  Xt bf16                -> reused as F bf16 after conv_t
    //  [33554432, 67108864)  T fp32
    //  [67108864, ...)       A_t bf16 (147456) | A_c bf16 (147456) | Wb bf16 (8192)
    __hip_bfloat16* Xc = (__hip_bfloat16*)ws;
    __hip_bfloat16* Xt = (__hip_bfloat16*)(ws + 16777216L);
    float* T = ws + 33554432L;
    float* Cc = out;                                     // d_out as scratch
    __hip_bfloat16* A_t = (__hip_bfloat16*)(ws + 67108864L);
    __hip_bfloat16* A_c = (__hip_bfloat16*)(ws + 67182592L);
    __hip_bfloat16* Wb = (__hip_bfloat16*)(ws + 67256320L);
    __hip_bfloat16* At_bf = Xc;                          // 67 MB, Xc dead after convs
    __hip_bfloat16* F_bf = Xt;                           // 67 MB, Xt dead after convs

    hipLaunchKernelGGL(k_prep, dim3(576), dim3(256), 0, stream, w_t, w_c, w_map, A_t, A_c, Wb);
    hipLaunchKernelGGL(k_trans_c, dim3(1024, 2), dim3(256), 0, stream, x, Xc);
    hipLaunchKernelGGL(k_trans_t, dim3(1024, 2), dim3(256), 0, stream, x, Xt);
    hipLaunchKernelGGL(k_conv_mfma, dim3(2048), dim3(256), 0, stream, Xt, A_t, b_t, T);
    hipLaunchKernelGGL(k_conv_mfma, dim3(2048), dim3(256), 0, stream, Xc, A_c, b_c, Cc);
    hipLaunchKernelGGL(k_attn, dim3(8192), dim3(128), 0, stream, Cc, T, At_bf);
    hipLaunchKernelGGL(k_f, dim3(1024), dim3(256), 0, stream, Cc, T, F_bf);
    hipLaunchKernelGGL(k_map, dim3(2048), dim3(256), 0, stream, x, F_bf, At_bf, Wb, b_map, out);
}

// Round 11
// 757.105 us; speedup vs baseline: 1.3580x; 1.0073x over previous
//
#include <hip/hip_runtime.h>
#include <hip/hip_bf16.h>
#include <math.h>

#define HWD 262144   // 64*64*64

typedef __attribute__((ext_vector_type(8))) short bf16x8;   // 8 bf16 (4 VGPRs)
typedef __attribute__((ext_vector_type(16))) float f32x16;  // MFMA 32x32 accumulator

__device__ inline unsigned short bfu(float f) {
    __hip_bfloat16 h = __float2bfloat16(f);
    return *reinterpret_cast<unsigned short*>(&h);
}

// ---------------- prep: weights -> bf16 GEMM layout A[ks 72][oc 128][kk 16]; w_map -> Wb bf16 ----
// K order: k = ((g*3+r)*3+s)*64 + z,  ks=k>>4, kk=k&15.
__global__ void k_prep(const float* __restrict__ w_t, const float* __restrict__ w_c,
                       const float* __restrict__ w_map,
                       __hip_bfloat16* __restrict__ A_t, __hip_bfloat16* __restrict__ A_c,
                       __hip_bfloat16* __restrict__ Wb) {
    int i = blockIdx.x * 256 + threadIdx.x;
    if (i < 147456) {
        int kk = i & 15, oc = (i >> 4) & 127, ks = i >> 11;
        int z4 = ks & 3, kq = ks >> 2;          // kq = (g*3+r)*3+s in [0,18)
        int g = kq / 9, tap = kq - 9 * g;       // tap = r*3+s
        int z = z4 * 16 + kk;
        // w_t (128,2,64,3,3): ((o*2+g)*64+kh)*9 + tap,  z=kh
        A_t[i] = __float2bfloat16(w_t[((oc * 2 + g) * 64 + z) * 9 + tap]);
        // w_c (128,2,3,3,64): ((o*2+g)*9+tap)*64 + kd,  z=kd
        A_c[i] = __float2bfloat16(w_c[((oc * 2 + g) * 9 + tap) * 64 + z]);
    }
    if (i < 8192) {
        Wb[i] = __float2bfloat16(w_map[i]);   // w_map is (C,2C) row-major = [c][k]
    }
}

__device__ inline void pack_row_bf16(__hip_bfloat16* dst, const float* src) {
    unsigned short u[16];
#pragma unroll
    for (int j = 0; j < 16; ++j) u[j] = bfu(src[j]);
    uint4* q = reinterpret_cast<uint4*>(dst);
    q[0] = *reinterpret_cast<const uint4*>(&u[0]);
    q[1] = *reinterpret_cast<const uint4*>(&u[8]);
}

// ---------------- transpose x (B,N,C) -> Xc bf16, z4-plane layout [cg][z4][h*w][16] ------------
__global__ void k_trans_c(const float* __restrict__ x, __hip_bfloat16* __restrict__ Xc) {
    __shared__ unsigned short tile[256][68];
    int b = blockIdx.y;
    long n0 = (long)blockIdx.x * 256;
    int t = threadIdx.x;
    const float4* xp4 = (const float4*)(x + ((long)b * HWD + n0) * 64);
#pragma unroll
    for (int i = 0; i < 16; ++i) {
        int f4i = i * 256 + t;
        float4 v = xp4[f4i];
        int nl = f4i >> 4, c4 = (f4i & 15) * 4;
        ushort4 u;
        u.x = bfu(v.x); u.y = bfu(v.y); u.z = bfu(v.z); u.w = bfu(v.w);
        *(ushort4*)&tile[nl][c4] = u;
    }
    __syncthreads();
    int c = t >> 2, hwl = t & 3;
    int hw0 = blockIdx.x * 4;
    __hip_bfloat16* dst0 = Xc + (long)(b * 64 + c) * HWD + (long)(hw0 + hwl) * 16;
#pragma unroll
    for (int z4 = 0; z4 < 4; ++z4) {
        unsigned short u[16];
#pragma unroll
        for (int j = 0; j < 16; ++j) u[j] = tile[hwl * 64 + z4 * 16 + j][c];
        __hip_bfloat16* dst = dst0 + z4 * 65536;
        *(uint4*)dst = *(const uint4*)&u[0];
        *(uint4*)(dst + 8) = *(const uint4*)&u[8];
    }
}

// ---------------- transpose x -> Xt bf16, z4-plane layout [cg][z4][w*d][16] (inner 16 = h) -----
__global__ void k_trans_t(const float* __restrict__ x, __hip_bfloat16* __restrict__ Xt) {
    __shared__ unsigned short tile[256][68];   // [wdl*64+h][c]
    int b = blockIdx.y;
    int wd0 = blockIdx.x * 4;
    int t = threadIdx.x;
    const float* xb = x + (long)b * HWD * 64 + (long)wd0 * 64;
#pragma unroll
    for (int i = 0; i < 16; ++i) {
        int idx = i * 256 + t;              // float4 id over 64 h x 64 f
        int h = idx >> 6, f = idx & 63;     // per h: 4 wd x 64 c = 1KB contiguous
        float4 v = *(const float4*)(xb + (long)h * 262144 + f * 4);
        int wdl = f >> 4, c4 = (f & 15) * 4;
        ushort4 u;
        u.x = bfu(v.x); u.y = bfu(v.y); u.z = bfu(v.z); u.w = bfu(v.w);
        *(ushort4*)&tile[wdl * 64 + h][c4] = u;
    }
    __syncthreads();
    int c = t >> 2, wdl = t & 3;
    __hip_bfloat16* dst0 = Xt + (long)(b * 64 + c) * HWD + (long)(wd0 + wdl) * 16;
#pragma unroll
    for (int z4 = 0; z4 < 4; ++z4) {
        unsigned short u[16];
#pragma unroll
        for (int j = 0; j < 16; ++j) u[j] = tile[wdl * 64 + z4 * 16 + j][c];
        __hip_bfloat16* dst = dst0 + z4 * 65536;
        *(uint4*)dst = *(const uint4*)&u[0];
        *(uint4*)(dst + 8) = *(const uint4*)&u[8];
    }
}

// ---------------- unified MFMA conv v6: kq-granular LDS staging, 16 MFMAs/wave per barrier ----
// (R9-benched: conv out of top-5.)
__global__ __launch_bounds__(256, 3) void k_conv_mfma(
        const __hip_bfloat16* __restrict__ X, const __hip_bfloat16* __restrict__ Aglob,
        const float* __restrict__ bias, float* __restrict__ Out) {
    int L = blockIdx.x;                       // 2048 = 64 grp * 32 pt
    int grp = (L & 7) * 8 + ((L >> 3) >> 5);  // XCD r handles grps [r*8, r*8+8)
    int pt = (L >> 3) & 31;
    int b = grp >> 5, ch = grp & 31;
    int p0 = pt * 2;
    const short* Xg = (const short*)(X + ((long)(b * 64 + 2 * ch)) * HWD);
    const short* Ag = (const short*)Aglob;
    int t = threadIdx.x;
    int lane = t & 63, wv = t >> 6;
    int O0 = (wv >> 1) * 64;              // wave oc base
    int N0 = (wv & 1) * 64;               // wave n base
    int lrow = lane & 31, lq = lane >> 5;

    // LDS: [buf][z4][khalf][128 rows x 8 shorts] = 32 KB
    __shared__ __align__(16) short Bsm[2][4][2][1024];

    f32x16 acc00 = {0}, acc01 = {0}, acc10 = {0}, acc11 = {0};

    int srow = t >> 1, shalf = t & 1;
    int spr = srow >> 6, sq = srow & 63;  // (p-row, q) of the staged B-row
    const uint4 zero4 = {0u, 0u, 0u, 0u};
    uint4 ld0, ld1, ld2, ld3;             // named (no arrays -> no scratch)

    auto stage_load = [&](int kq) {
        int g = (kq >= 9) ? 1 : 0;
        int tap = kq - 9 * g;
        int r = tap / 3, s = tap - 3 * r;
        int pp = p0 + spr + r - 1, qq = sq + s - 1;
        bool ok = ((unsigned)pp < 64u) && ((unsigned)qq < 64u);
        const short* px = Xg + (long)g * HWD + (pp * 64 + qq) * 16 + shalf * 8;
        ld0 = ok ? *(const uint4*)(px)           : zero4;
        ld1 = ok ? *(const uint4*)(px + 65536)   : zero4;
        ld2 = ok ? *(const uint4*)(px + 131072)  : zero4;
        ld3 = ok ? *(const uint4*)(px + 196608)  : zero4;
    };
    auto stage_write = [&](int buf) {
        *(uint4*)&Bsm[buf][0][shalf][srow * 8] = ld0;
        *(uint4*)&Bsm[buf][1][shalf][srow * 8] = ld1;
        *(uint4*)&Bsm[buf][2][shalf][srow * 8] = ld2;
        *(uint4*)&Bsm[buf][3][shalf][srow * 8] = ld3;
    };

    stage_load(0);
    stage_write(0);
    __syncthreads();

    int buf = 0;
    for (int kq = 0; kq < 18; ++kq) {
        if (kq < 17) stage_load(kq + 1);       // in flight across the 16-MFMA cluster
#pragma unroll
        for (int z4 = 0; z4 < 4; ++z4) {
            int ks = kq * 4 + z4;
            const short* Apk = Ag + ks * 2048 + (O0 + lrow) * 16 + lq * 8;
            uint4 a0u = *(const uint4*)(Apk);
            uint4 a1u = *(const uint4*)(Apk + 512);
            bf16x8 a0 = *(bf16x8*)&a0u;
            bf16x8 a1 = *(bf16x8*)&a1u;
            bf16x8 b0 = *(const bf16x8*)&Bsm[buf][z4][lq][(N0 + lrow) * 8];
            bf16x8 b1 = *(const bf16x8*)&Bsm[buf][z4][lq][(N0 + 32 + lrow) * 8];
            acc00 = __builtin_amdgcn_mfma_f32_32x32x16_bf16(a0, b0, acc00, 0, 0, 0);
            acc01 = __builtin_amdgcn_mfma_f32_32x32x16_bf16(a0, b1, acc01, 0, 0, 0);
            acc10 = __builtin_amdgcn_mfma_f32_32x32x16_bf16(a1, b0, acc10, 0, 0, 0);
            acc11 = __builtin_amdgcn_mfma_f32_32x32x16_bf16(a1, b1, acc11, 0, 0, 0);
        }
        if (kq < 17) {
            stage_write(buf ^ 1);
            __syncthreads();
            buf ^= 1;
        }
    }

    // store: C/D layout col=lane&31, row=(reg&3)+8*(reg>>2)+4*(lane>>5)
    long base0 = ((long)(b * 64 + 2 * ch)) * HWD + (long)p0 * 64;
    int n0l = N0 + lrow, n1l = N0 + 32 + lrow;
    long noff0 = (long)(n0l >> 6) * 64 + (n0l & 63);
    long noff1 = (long)(n1l >> 6) * 64 + (n1l & 63);
#pragma unroll
    for (int reg = 0; reg < 16; ++reg) {
        int row = (reg & 3) + 8 * (reg >> 2) + 4 * lq;
        int oc0 = O0 + row, oc1 = O0 + 32 + row;
        long cb0 = base0 + (long)(oc0 >> 6) * HWD + (long)(oc0 & 63) * 4096;
        long cb1 = base0 + (long)(oc1 >> 6) * HWD + (long)(oc1 & 63) * 4096;
        float bs0 = bias[oc0], bs1 = bias[oc1];
        Out[cb0 + noff0] = acc00[reg] + bs0;
        Out[cb0 + noff1] = acc01[reg] + bs0;
        Out[cb1 + noff0] = acc10[reg] + bs1;
        Out[cb1 + noff1] = acc11[reg] + bs1;
    }
}

// ---------------- attn v2: At[b,c,h,w2,d] = sum_w Cc[b,c,w2,h,w] * T[b,c,w2,w,d] (bf16 out) ----
__global__ __launch_bounds__(128) void k_attn(const float* __restrict__ Cc,
        const float* __restrict__ T, __hip_bfloat16* __restrict__ At) {
    __shared__ float As[64][65];   // [h][w]
    __shared__ float Bs[64][64];   // [w][d]
    int bc = blockIdx.x >> 6, w2 = blockIdx.x & 63;
    const float4* Ap4 = (const float4*)(Cc + ((long)bc * 64 + w2) * 4096);
    const float4* Bp4 = (const float4*)(T + ((long)bc * 64 + w2) * 4096);
    int t = threadIdx.x;
#pragma unroll
    for (int i = 0; i < 8; ++i) {
        int f = i * 128 + t;               // float4 id, 1024 total
        int r = f >> 4, q4 = (f & 15) * 4;
        float4 v = Ap4[f];
        As[r][q4 + 0] = v.x; As[r][q4 + 1] = v.y; As[r][q4 + 2] = v.z; As[r][q4 + 3] = v.w;
        float4 w = Bp4[f];
        *(float4*)&Bs[r][q4] = w;
    }
    __syncthreads();
    int h2 = t >> 2, dg = (t & 3) * 16;
    f32x16 acc0 = {0}, acc1 = {0};
    for (int k = 0; k < 64; ++k) {
        float a0 = As[h2][k];
        float a1 = As[h2 + 32][k];
        const float* br = &Bs[k][dg];
#pragma unroll
        for (int i = 0; i < 16; ++i) {
            acc0[i] = fmaf(a0, br[i], acc0[i]);
            acc1[i] = fmaf(a1, br[i], acc1[i]);
        }
    }
    float tmp[16];
    __hip_bfloat16* Ab = At + (long)bc * HWD + (long)h2 * 4096 + w2 * 64 + dg;
#pragma unroll
    for (int i = 0; i < 16; ++i) tmp[i] = acc0[i];
    pack_row_bf16(Ab, tmp);
#pragma unroll
    for (int i = 0; i < 16; ++i) tmp[i] = acc1[i];
    pack_row_bf16(Ab + 32L * 4096, tmp);
}

// ---------------- f v3: F[b,c,h,w,d] = sum_w2 Cc[b,c,w2,h,w] * T[b,c,w2,w,d] (bf16 out) ----
__global__ __launch_bounds__(256, 2) void k_f(const float* __restrict__ Cc,
        const float* __restrict__ T, __hip_bfloat16* __restrict__ F) {
    __shared__ float As[16][64][8];   // [kk][h][w]        32 KB
    __shared__ float Bs[16][8][68];   // [kk][w][d(+pad)]  34 KB
    int L = blockIdx.x;               // 1024 = 128 bc * 8 wt
    int xcd = L & 7, j = L >> 3;      // j 0..127
    int bc = xcd * 16 + (j >> 3), wt = j & 7;
    const float* Ab = Cc + (long)bc * HWD + wt * 8;
    const float* Bb = T + (long)bc * HWD + wt * 8 * 64;
    int t = threadIdx.x;
    int w = t & 7, h2 = t >> 3;       // h2 in 0..31
    f32x16 p00 = {0}, p01 = {0}, p02 = {0}, p03 = {0};
    f32x16 p10 = {0}, p11 = {0}, p12 = {0}, p13 = {0};

    for (int w2c = 0; w2c < 4; ++w2c) {
        __syncthreads();
        // A stage: 16 kk x 64 h x 2 half-float4 (32B contiguous per (kk,h))
#pragma unroll
        for (int i = 0; i < 8; ++i) {
            int f = i * 256 + t;                       // 0..2047
            int half = f & 1, hh = (f >> 1) & 63, kk = f >> 7;
            float4 v = *(const float4*)(Ab + (long)(w2c * 16 + kk) * 4096 + hh * 64 + half * 4);
            *(float4*)&As[kk][hh][half * 4] = v;
        }
        // B stage: 16 kk x 8 w x 16 float4 (256B contiguous per (kk,w))
#pragma unroll
        for (int i = 0; i < 8; ++i) {
            int f = i * 256 + t;
            int d4 = f & 15, ww = (f >> 4) & 7, kk = f >> 7;
            float4 v = *(const float4*)(Bb + (long)(w2c * 16 + kk) * 4096 + ww * 64 + d4 * 4);
            *(float4*)&Bs[kk][ww][d4 * 4] = v;
        }
        __syncthreads();
        for (int kk = 0; kk < 16; ++kk) {
            float a0 = As[kk][h2][w];
            float a1 = As[kk][h2 + 32][w];
            const float* br = &Bs[kk][w][0];
#pragma unroll
            for (int i = 0; i < 16; ++i) {
                p00[i] = fmaf(a0, br[i], p00[i]);
                p01[i] = fmaf(a0, br[16 + i], p01[i]);
                p02[i] = fmaf(a0, br[32 + i], p02[i]);
                p03[i] = fmaf(a0, br[48 + i], p03[i]);
                p10[i] = fmaf(a1, br[i], p10[i]);
                p11[i] = fmaf(a1, br[16 + i], p11[i]);
                p12[i] = fmaf(a1, br[32 + i], p12[i]);
                p13[i] = fmaf(a1, br[48 + i], p13[i]);
            }
        }
    }
    // store: F[bc][h][wt*8+w][d], 128B per h-row (contiguous)
    __hip_bfloat16* Fp = F + (long)bc * HWD + (long)h2 * 4096 + (wt * 8 + w) * 64;
    float tmp[16];
#pragma unroll
    for (int i = 0; i < 16; ++i) tmp[i] = p00[i];
    pack_row_bf16(Fp, tmp);
#pragma unroll
    for (int i = 0; i < 16; ++i) tmp[i] = p01[i];
    pack_row_bf16(Fp + 16, tmp);
#pragma unroll
    for (int i = 0; i < 16; ++i) tmp[i] = p02[i];
    pack_row_bf16(Fp + 32, tmp);
#pragma unroll
    for (int i = 0; i < 16; ++i) tmp[i] = p03[i];
    pack_row_bf16(Fp + 48, tmp);
    __hip_bfloat16* Fq = Fp + 32L * 4096;
#pragma unroll
    for (int i = 0; i < 16; ++i) tmp[i] = p10[i];
    pack_row_bf16(Fq, tmp);
#pragma unroll
    for (int i = 0; i < 16; ++i) tmp[i] = p11[i];
    pack_row_bf16(Fq + 16, tmp);
#pragma unroll
    for (int i = 0; i < 16; ++i) tmp[i] = p12[i];
    pack_row_bf16(Fq + 32, tmp);
#pragma unroll
    for (int i = 0; i < 16; ++i) tmp[i] = p13[i];
    pack_row_bf16(Fq + 48, tmp);
}

// ---------------- map v6 (MFMA): out[n][c] = gelu( sum_k P[n][k] Wb[k][c] + b_map[c] ) ----
// P[n][k<64] = bf16(x[n][k] * F[k][n]),  P[n][k>=64] = At[k-64][n].
// R10 diagnosis: v5 neutral -> k_map is LATENCY-bound (Mfma 2.7%, VALU 31%, BW 38%,
// occ 29%: nothing saturated; stage->barrier->consume exposes full HBM latency x8 chunks).
// v6: double-buffered xs/fa (49.8KB), loads for kc+1 issued BEFORE compute of kc (T14);
// LDS write after compute; ONE barrier per chunk (8 vs 16); launch_bounds(256,3) -> 3
// blocks/CU (149KB LDS). Named staging regs only (rule #20).
__global__ __launch_bounds__(256, 3) void k_map(const float* __restrict__ x,
        const __hip_bfloat16* __restrict__ F, const __hip_bfloat16* __restrict__ At,
        const __hip_bfloat16* __restrict__ Wb, const float* __restrict__ b_map,
        float* __restrict__ out) {
    __shared__ float xs[2][16][257];          // 32896 B
    __shared__ __hip_bfloat16 fa[2][16][264]; // 16896 B

    int t = threadIdx.x;
    long n0 = (long)blockIdx.x * 256;
    int b = (int)(n0 >> 18);
    long nn0 = n0 & (HWD - 1);
    const float* xblk = x + n0 * 64;
    const __hip_bfloat16* Fb = F + (long)b * 64 * HWD + nn0;
    const __hip_bfloat16* Ab = At + (long)b * 64 * HWD + nn0;

    int lane = t & 63, wv = t >> 6;
    int lrow = lane & 31, lhalf = lane >> 5;

    // preload W fragments: B-operand frag for ks=kc is W[c][kc*16 + lhalf*8 ..+8]
    const short* Wp = (const short*)Wb;
    bf16x8 wb0[8], wb1[8];                    // static-indexed in unrolled loop only
#pragma unroll
    for (int kc = 0; kc < 8; ++kc) {
        uint4 u0 = *(const uint4*)(Wp + lrow * 128 + kc * 16 + lhalf * 8);
        uint4 u1 = *(const uint4*)(Wp + (32 + lrow) * 128 + kc * 16 + lhalf * 8);
        wb0[kc] = *(bf16x8*)&u0;
        wb1[kc] = *(bf16x8*)&u1;
    }

    f32x16 acc00 = {0}, acc01 = {0}, acc10 = {0}, acc11 = {0};

    // named staging registers (no arrays -> no scratch)
    float4 xa, xb_, xc_, xd;
    uint4 fe, ff;
    int nrA = t >> 2, j4A = (t & 3) * 4;                        // i2 = 0..3 offsets derived
    int rowF0 = t >> 5, segF0 = t & 31;                         // it = 0
    int rowF1 = (256 + t) >> 5, segF1 = t & 31;                 // it = 1

    auto load_chunk = [&](int kc) {
        if (kc < 4) {
            xa  = *(const float4*)(xblk + (nrA +   0) * 64 + kc * 16 + j4A);
            xb_ = *(const float4*)(xblk + (nrA +  64) * 64 + kc * 16 + j4A);
            xc_ = *(const float4*)(xblk + (nrA + 128) * 64 + kc * 16 + j4A);
            xd  = *(const float4*)(xblk + (nrA + 192) * 64 + kc * 16 + j4A);
            fe = *(const uint4*)(Fb + (long)(kc * 16 + rowF0) * HWD + segF0 * 8);
            ff = *(const uint4*)(Fb + (long)(kc * 16 + rowF1) * HWD + segF1 * 8);
        } else {
            fe = *(const uint4*)(Ab + (long)((kc - 4) * 16 + rowF0) * HWD + segF0 * 8);
            ff = *(const uint4*)(Ab + (long)((kc - 4) * 16 + rowF1) * HWD + segF1 * 8);
        }
    };
    auto write_chunk = [&](int kc, int buf) {
        if (kc < 4) {
            xs[buf][j4A + 0][nrA +   0] = xa.x;
            xs[buf][j4A + 1][nrA +   0] = xa.y;
            xs[buf][j4A + 2][nrA +   0] = xa.z;
            xs[buf][j4A + 3][nrA +   0] = xa.w;
            xs[buf][j4A + 0][nrA +  64] = xb_.x;
            xs[buf][j4A + 1][nrA +  64] = xb_.y;
            xs[buf][j4A + 2][nrA +  64] = xb_.z;
            xs[buf][j4A + 3][nrA +  64] = xb_.w;
            xs[buf][j4A + 0][nrA + 128] = xc_.x;
            xs[buf][j4A + 1][nrA + 128] = xc_.y;
            xs[buf][j4A + 2][nrA + 128] = xc_.z;
            xs[buf][j4A + 3][nrA + 128] = xc_.w;
            xs[buf][j4A + 0][nrA + 192] = xd.x;
            xs[buf][j4A + 1][nrA + 192] = xd.y;
            xs[buf][j4A + 2][nrA + 192] = xd.z;
            xs[buf][j4A + 3][nrA + 192] = xd.w;
        }
        *(uint4*)&fa[buf][rowF0][segF0 * 8] = fe;
        *(uint4*)&fa[buf][rowF1][segF1 * 8] = ff;
    };

    load_chunk(0);
    write_chunk(0, 0);
    __syncthreads();

#pragma unroll
    for (int kc = 0; kc < 8; ++kc) {
        int buf = kc & 1;
        if (kc < 7) load_chunk(kc + 1);        // HBM latency hides under compute below
        // build P row t (16 bf16) in registers
        unsigned short pv[16];
        if (kc < 4) {
#pragma unroll
            for (int k2 = 0; k2 < 16; ++k2) {
                float p = xs[buf][k2][t] * __bfloat162float(fa[buf][k2][t]);
                pv[k2] = bfu(p);
            }
        } else {
#pragma unroll
            for (int k2 = 0; k2 < 16; ++k2)
                pv[k2] = *reinterpret_cast<const unsigned short*>(&fa[buf][k2][t]);
        }
        unsigned lo0 = (unsigned)pv[0]  | ((unsigned)pv[1]  << 16);
        unsigned lo1 = (unsigned)pv[2]  | ((unsigned)pv[3]  << 16);
        unsigned lo2 = (unsigned)pv[4]  | ((unsigned)pv[5]  << 16);
        unsigned lo3 = (unsigned)pv[6]  | ((unsigned)pv[7]  << 16);
        unsigned hi0 = (unsigned)pv[8]  | ((unsigned)pv[9]  << 16);
        unsigned hi1 = (unsigned)pv[10] | ((unsigned)pv[11] << 16);
        unsigned hi2 = (unsigned)pv[12] | ((unsigned)pv[13] << 16);
        unsigned hi3 = (unsigned)pv[14] | ((unsigned)pv[15] << 16);
        // A-frag assembly via intra-wave shuffles (no LDS, no barrier):
        int sl0 = lane & 31, sl1 = lane | 32;
        bool lowh = lane < 32;
        unsigned s00 = __shfl(hi0, sl0), s01 = __shfl(hi1, sl0);
        unsigned s02 = __shfl(hi2, sl0), s03 = __shfl(hi3, sl0);
        unsigned r00 = __shfl(lo0, sl1), r01 = __shfl(lo1, sl1);
        unsigned r02 = __shfl(lo2, sl1), r03 = __shfl(lo3, sl1);
        uint4 ua0, ua1;
        ua0.x = lowh ? lo0 : s00; ua0.y = lowh ? lo1 : s01;
        ua0.z = lowh ? lo2 : s02; ua0.w = lowh ? lo3 : s03;
        ua1.x = lowh ? r00 : hi0; ua1.y = lowh ? r01 : hi1;
        ua1.z = lowh ? r02 : hi2; ua1.w = lowh ? r03 : hi3;
        bf16x8 a0 = *(bf16x8*)&ua0;
        bf16x8 a1 = *(bf16x8*)&ua1;
        acc00 = __builtin_amdgcn_mfma_f32_32x32x16_bf16(a0, wb0[kc], acc00, 0, 0, 0);
        acc01 = __builtin_amdgcn_mfma_f32_32x32x16_bf16(a0, wb1[kc], acc01, 0, 0, 0);
        acc10 = __builtin_amdgcn_mfma_f32_32x32x16_bf16(a1, wb0[kc], acc10, 0, 0, 0);
        acc11 = __builtin_amdgcn_mfma_f32_32x32x16_bf16(a1, wb1[kc], acc11, 0, 0, 0);
        if (kc < 7) {
            write_chunk(kc + 1, buf ^ 1);      // buf^1's readers finished before last barrier
            __syncthreads();
        }
    }

    // epilogue: bias + exact GELU + store.
    // D layout: col(c) = lane&31, row(n) = (reg&3)+8*(reg>>2)+4*lhalf
    float bs0 = b_map[lrow];
    float bs1 = b_map[32 + lrow];
    const float inv_sqrt2 = 0.70710678118654752440f;
    float* ob = out + (n0 + wv * 64) * 64;
#pragma unroll
    for (int reg = 0; reg < 16; ++reg) {
        int nrow = (reg & 3) + 8 * (reg >> 2) + 4 * lhalf;
        float v00 = acc00[reg] + bs0;
        float v01 = acc01[reg] + bs1;
        float v10 = acc10[reg] + bs0;
        float v11 = acc11[reg] + bs1;
        v00 = 0.5f * v00 * (1.f + erff(v00 * inv_sqrt2));
        v01 = 0.5f * v01 * (1.f + erff(v01 * inv_sqrt2));
        v10 = 0.5f * v10 * (1.f + erff(v10 * inv_sqrt2));
        v11 = 0.5f * v11 * (1.f + erff(v11 * inv_sqrt2));
        ob[(long)nrow * 64 + lrow] = v00;            // lanes 0-31 + 32-63: 2x128B contig
        ob[(long)nrow * 64 + 32 + lrow] = v01;
        ob[(long)(32 + nrow) * 64 + lrow] = v10;
        ob[(long)(32 + nrow) * 64 + 32 + lrow] = v11;
    }
}

extern "C" void kernel_launch(void* const* d_in, const int* in_sizes, int n_in,
                              void* d_out, int out_size, void* d_ws, size_t ws_size,
                              hipStream_t stream) {
    const float* x     = (const float*)d_in[0];
    const float* w_t   = (const float*)d_in[1];
    const float* b_t   = (const float*)d_in[2];
    const float* w_c   = (const float*)d_in[3];
    const float* b_c   = (const float*)d_in[4];
    const float* w_map = (const float*)d_in[5];
    const float* b_map = (const float*)d_in[6];
    float* out = (float*)d_out;
    float* ws = (float*)d_ws;

    // ws layout (float offsets), ~269 MB total:
    //  [0,        16777216)  Xc bf16  (33.5M elem)  -> reused as At bf16 after conv_c
    //  [16777216, 33554432)  Xt bf16                -> reused as F bf16 after conv_t
    //  [33554432, 67108864)  T fp32
    //  [67108864, ...)       A_t bf16 (147456) | A_c bf16 (147456) | Wb bf16 (8192)
    __hip_bfloat16* Xc = (__hip_bfloat16*)ws;
    __hip_bfloat16* Xt = (__hip_bfloat16*)(ws + 16777216L);
    float* T = ws + 33554432L;
    float* Cc = out;                                     // d_out as scratch
    __hip_bfloat16* A_t = (__hip_bfloat16*)(ws + 67108864L);
    __hip_bfloat16* A_c = (__hip_bfloat16*)(ws + 67182592L);
    __hip_bfloat16* Wb = (__hip_bfloat16*)(ws + 67256320L);
    __hip_bfloat16* At_bf = Xc;                          // 67 MB, Xc dead after convs
    __hip_bfloat16* F_bf = Xt;                           // 67 MB, Xt dead after convs

    hipLaunchKernelGGL(k_prep, dim3(576), dim3(256), 0, stream, w_t, w_c, w_map, A_t, A_c, Wb);
    hipLaunchKernelGGL(k_trans_c, dim3(1024, 2), dim3(256), 0, stream, x, Xc);
    hipLaunchKernelGGL(k_trans_t, dim3(1024, 2), dim3(256), 0, stream, x, Xt);
    hipLaunchKernelGGL(k_conv_mfma, dim3(2048), dim3(256), 0, stream, Xt, A_t, b_t, T);
    hipLaunchKernelGGL(k_conv_mfma, dim3(2048), dim3(256), 0, stream, Xc, A_c, b_c, Cc);
    hipLaunchKernelGGL(k_attn, dim3(8192), dim3(128), 0, stream, Cc, T, At_bf);
    hipLaunchKernelGGL(k_f, dim3(1024), dim3(256), 0, stream, Cc, T, F_bf);
    hipLaunchKernelGGL(k_map, dim3(2048), dim3(256), 0, stream, x, F_bf, At_bf, Wb, b_map, out);
}

// Round 12
// 734.718 us; speedup vs baseline: 1.3994x; 1.0305x over previous
//
#include <hip/hip_runtime.h>
#include <hip/hip_bf16.h>
#include <math.h>

#define HWD 262144   // 64*64*64

typedef __attribute__((ext_vector_type(8))) short bf16x8;   // 8 bf16 (4 VGPRs)
typedef __attribute__((ext_vector_type(16))) float f32x16;  // MFMA 32x32 accumulator

__device__ inline unsigned short bfu(float f) {
    __hip_bfloat16 h = __float2bfloat16(f);
    return *reinterpret_cast<unsigned short*>(&h);
}

// ---------------- prep: weights -> bf16 GEMM layout A[ks 72][oc 128][kk 16]; w_map -> Wb bf16 ----
// K order: k = ((g*3+r)*3+s)*64 + z,  ks=k>>4, kk=k&15.
__global__ void k_prep(const float* __restrict__ w_t, const float* __restrict__ w_c,
                       const float* __restrict__ w_map,
                       __hip_bfloat16* __restrict__ A_t, __hip_bfloat16* __restrict__ A_c,
                       __hip_bfloat16* __restrict__ Wb) {
    int i = blockIdx.x * 256 + threadIdx.x;
    if (i < 147456) {
        int kk = i & 15, oc = (i >> 4) & 127, ks = i >> 11;
        int z4 = ks & 3, kq = ks >> 2;          // kq = (g*3+r)*3+s in [0,18)
        int g = kq / 9, tap = kq - 9 * g;       // tap = r*3+s
        int z = z4 * 16 + kk;
        // w_t (128,2,64,3,3): ((o*2+g)*64+kh)*9 + tap,  z=kh
        A_t[i] = __float2bfloat16(w_t[((oc * 2 + g) * 64 + z) * 9 + tap]);
        // w_c (128,2,3,3,64): ((o*2+g)*9+tap)*64 + kd,  z=kd
        A_c[i] = __float2bfloat16(w_c[((oc * 2 + g) * 9 + tap) * 64 + z]);
    }
    if (i < 8192) {
        Wb[i] = __float2bfloat16(w_map[i]);   // w_map is (C,2C) row-major = [c][k]
    }
}

__device__ inline void pack_row_bf16(__hip_bfloat16* dst, const float* src) {
    unsigned short u[16];
#pragma unroll
    for (int j = 0; j < 16; ++j) u[j] = bfu(src[j]);
    uint4* q = reinterpret_cast<uint4*>(dst);
    q[0] = *reinterpret_cast<const uint4*>(&u[0]);
    q[1] = *reinterpret_cast<const uint4*>(&u[8]);
}

// ---------------- transpose x (B,N,C) -> Xc bf16, z4-plane layout [cg][z4][h*w][16] ------------
__global__ void k_trans_c(const float* __restrict__ x, __hip_bfloat16* __restrict__ Xc) {
    __shared__ unsigned short tile[256][68];
    int b = blockIdx.y;
    long n0 = (long)blockIdx.x * 256;
    int t = threadIdx.x;
    const float4* xp4 = (const float4*)(x + ((long)b * HWD + n0) * 64);
#pragma unroll
    for (int i = 0; i < 16; ++i) {
        int f4i = i * 256 + t;
        float4 v = xp4[f4i];
        int nl = f4i >> 4, c4 = (f4i & 15) * 4;
        ushort4 u;
        u.x = bfu(v.x); u.y = bfu(v.y); u.z = bfu(v.z); u.w = bfu(v.w);
        *(ushort4*)&tile[nl][c4] = u;
    }
    __syncthreads();
    int c = t >> 2, hwl = t & 3;
    int hw0 = blockIdx.x * 4;
    __hip_bfloat16* dst0 = Xc + (long)(b * 64 + c) * HWD + (long)(hw0 + hwl) * 16;
#pragma unroll
    for (int z4 = 0; z4 < 4; ++z4) {
        unsigned short u[16];
#pragma unroll
        for (int j = 0; j < 16; ++j) u[j] = tile[hwl * 64 + z4 * 16 + j][c];
        __hip_bfloat16* dst = dst0 + z4 * 65536;
        *(uint4*)dst = *(const uint4*)&u[0];
        *(uint4*)(dst + 8) = *(const uint4*)&u[8];
    }
}

// ---------------- transpose x -> Xt bf16, z4-plane layout [cg][z4][w*d][16] (inner 16 = h) -----
__global__ void k_trans_t(const float* __restrict__ x, __hip_bfloat16* __restrict__ Xt) {
    __shared__ unsigned short tile[256][68];   // [wdl*64+h][c]
    int b = blockIdx.y;
    int wd0 = blockIdx.x * 4;
    int t = threadIdx.x;
    const float* xb = x + (long)b * HWD * 64 + (long)wd0 * 64;
#pragma unroll
    for (int i = 0; i < 16; ++i) {
        int idx = i * 256 + t;              // float4 id over 64 h x 64 f
        int h = idx >> 6, f = idx & 63;     // per h: 4 wd x 64 c = 1KB contiguous
        float4 v = *(const float4*)(xb + (long)h * 262144 + f * 4);
        int wdl = f >> 4, c4 = (f & 15) * 4;
        ushort4 u;
        u.x = bfu(v.x); u.y = bfu(v.y); u.z = bfu(v.z); u.w = bfu(v.w);
        *(ushort4*)&tile[wdl * 64 + h][c4] = u;
    }
    __syncthreads();
    int c = t >> 2, wdl = t & 3;
    __hip_bfloat16* dst0 = Xt + (long)(b * 64 + c) * HWD + (long)(wd0 + wdl) * 16;
#pragma unroll
    for (int z4 = 0; z4 < 4; ++z4) {
        unsigned short u[16];
#pragma unroll
        for (int j = 0; j < 16; ++j) u[j] = tile[wdl * 64 + z4 * 16 + j][c];
        __hip_bfloat16* dst = dst0 + z4 * 65536;
        *(uint4*)dst = *(const uint4*)&u[0];
        *(uint4*)(dst + 8) = *(const uint4*)&u[8];
    }
}

// ---------------- unified MFMA conv v7: R9 structure, both convs MERGED in one dispatch -------
// (tail of conv_t overlaps head of conv_c; per-half logic unchanged from the benched v6)
__global__ __launch_bounds__(256, 3) void k_conv_mfma(
        const __hip_bfloat16* __restrict__ Xt, const __hip_bfloat16* __restrict__ At_,
        const float* __restrict__ bt, float* __restrict__ OutT,
        const __hip_bfloat16* __restrict__ Xc, const __hip_bfloat16* __restrict__ Ac_,
        const float* __restrict__ bcb, float* __restrict__ OutC) {
    int Lfull = blockIdx.x;                   // 4096 = 2 halves x 2048
    int halfk = Lfull >> 11;
    int L = Lfull & 2047;                     // 2048 = 64 grp * 32 pt
    const __hip_bfloat16* X = halfk ? Xc : Xt;
    const __hip_bfloat16* Aglob = halfk ? Ac_ : At_;
    const float* bias = halfk ? bcb : bt;
    float* Out = halfk ? OutC : OutT;

    int grp = (L & 7) * 8 + ((L >> 3) >> 5);  // XCD r handles grps [r*8, r*8+8)
    int pt = (L >> 3) & 31;
    int b = grp >> 5, ch = grp & 31;
    int p0 = pt * 2;
    const short* Xg = (const short*)(X + ((long)(b * 64 + 2 * ch)) * HWD);
    const short* Ag = (const short*)Aglob;
    int t = threadIdx.x;
    int lane = t & 63, wv = t >> 6;
    int O0 = (wv >> 1) * 64;              // wave oc base
    int N0 = (wv & 1) * 64;               // wave n base
    int lrow = lane & 31, lq = lane >> 5;

    // LDS: [buf][z4][khalf][128 rows x 8 shorts] = 32 KB
    __shared__ __align__(16) short Bsm[2][4][2][1024];

    f32x16 acc00 = {0}, acc01 = {0}, acc10 = {0}, acc11 = {0};

    int srow = t >> 1, shalf = t & 1;
    int spr = srow >> 6, sq = srow & 63;  // (p-row, q) of the staged B-row
    const uint4 zero4 = {0u, 0u, 0u, 0u};
    uint4 ld0, ld1, ld2, ld3;             // named (no arrays -> no scratch)

    auto stage_load = [&](int kq) {
        int g = (kq >= 9) ? 1 : 0;
        int tap = kq - 9 * g;
        int r = tap / 3, s = tap - 3 * r;
        int pp = p0 + spr + r - 1, qq = sq + s - 1;
        bool ok = ((unsigned)pp < 64u) && ((unsigned)qq < 64u);
        const short* px = Xg + (long)g * HWD + (pp * 64 + qq) * 16 + shalf * 8;
        ld0 = ok ? *(const uint4*)(px)           : zero4;
        ld1 = ok ? *(const uint4*)(px + 65536)   : zero4;
        ld2 = ok ? *(const uint4*)(px + 131072)  : zero4;
        ld3 = ok ? *(const uint4*)(px + 196608)  : zero4;
    };
    auto stage_write = [&](int buf) {
        *(uint4*)&Bsm[buf][0][shalf][srow * 8] = ld0;
        *(uint4*)&Bsm[buf][1][shalf][srow * 8] = ld1;
        *(uint4*)&Bsm[buf][2][shalf][srow * 8] = ld2;
        *(uint4*)&Bsm[buf][3][shalf][srow * 8] = ld3;
    };

    stage_load(0);
    stage_write(0);
    __syncthreads();

    int buf = 0;
    for (int kq = 0; kq < 18; ++kq) {
        if (kq < 17) stage_load(kq + 1);       // in flight across the 16-MFMA cluster
#pragma unroll
        for (int z4 = 0; z4 < 4; ++z4) {
            int ks = kq * 4 + z4;
            const short* Apk = Ag + ks * 2048 + (O0 + lrow) * 16 + lq * 8;
            uint4 a0u = *(const uint4*)(Apk);
            uint4 a1u = *(const uint4*)(Apk + 512);
            bf16x8 a0 = *(bf16x8*)&a0u;
            bf16x8 a1 = *(bf16x8*)&a1u;
            bf16x8 b0 = *(const bf16x8*)&Bsm[buf][z4][lq][(N0 + lrow) * 8];
            bf16x8 b1 = *(const bf16x8*)&Bsm[buf][z4][lq][(N0 + 32 + lrow) * 8];
            acc00 = __builtin_amdgcn_mfma_f32_32x32x16_bf16(a0, b0, acc00, 0, 0, 0);
            acc01 = __builtin_amdgcn_mfma_f32_32x32x16_bf16(a0, b1, acc01, 0, 0, 0);
            acc10 = __builtin_amdgcn_mfma_f32_32x32x16_bf16(a1, b0, acc10, 0, 0, 0);
            acc11 = __builtin_amdgcn_mfma_f32_32x32x16_bf16(a1, b1, acc11, 0, 0, 0);
        }
        if (kq < 17) {
            stage_write(buf ^ 1);
            __syncthreads();
            buf ^= 1;
        }
    }

    // store: C/D layout col=lane&31, row=(reg&3)+8*(reg>>2)+4*(lane>>5)
    long base0 = ((long)(b * 64 + 2 * ch)) * HWD + (long)p0 * 64;
    int n0l = N0 + lrow, n1l = N0 + 32 + lrow;
    long noff0 = (long)(n0l >> 6) * 64 + (n0l & 63);
    long noff1 = (long)(n1l >> 6) * 64 + (n1l & 63);
#pragma unroll
    for (int reg = 0; reg < 16; ++reg) {
        int row = (reg & 3) + 8 * (reg >> 2) + 4 * lq;
        int oc0 = O0 + row, oc1 = O0 + 32 + row;
        long cb0 = base0 + (long)(oc0 >> 6) * HWD + (long)(oc0 & 63) * 4096;
        long cb1 = base0 + (long)(oc1 >> 6) * HWD + (long)(oc1 & 63) * 4096;
        float bs0 = bias[oc0], bs1 = bias[oc1];
        Out[cb0 + noff0] = acc00[reg] + bs0;
        Out[cb0 + noff1] = acc01[reg] + bs0;
        Out[cb1 + noff0] = acc10[reg] + bs1;
        Out[cb1 + noff1] = acc11[reg] + bs1;
    }
}

// ---------------- attn v3 (MFMA): At[bc,h,w2,d] = sum_w Cc[bc,w2,h,w] * T[bc,w2,w,d] ----------
// Per block (bc,w2): P[64h][64d] = M[64h][64w] x N[64w][64d], both row-major contiguous.
// Stage bf16: Ms[h][w]; Ns[d][w] (T transposed so the B-frag is contiguous per lane).
// 4 waves = 4 output quadrants, 4 MFMAs each. Replaces the LDS-bound VALU loop (~8k
// cyc/block). XCD swizzle keeps each bc's 2MB (Cc+T) on one XCD L2 (k_f's pattern).
// Numerics: inputs rounded to bf16 (est +<=1 ulp on At; acc stays fp32).
__global__ __launch_bounds__(256) void k_attn(const float* __restrict__ Cc,
        const float* __restrict__ T, __hip_bfloat16* __restrict__ At) {
    __shared__ __align__(16) __hip_bfloat16 Ms[64][72];   // [h][w] 9216B, 144B rows (16B-mult)
    __shared__ __align__(16) __hip_bfloat16 Ns[64][72];   // [d][w] 9216B, transposed T
    int L = blockIdx.x;                        // 8192 = 128 bc * 64 w2
    int xcd = L & 7, j = L >> 3;
    int bc = xcd * 16 + (j >> 6), w2 = j & 63;
    const float* Ap = Cc + ((long)bc * 64 + w2) * 4096;
    const float* Bp = T + ((long)bc * 64 + w2) * 4096;
    int t = threadIdx.x;
#pragma unroll
    for (int i = 0; i < 4; ++i) {
        int f = i * 256 + t;                   // float4 id, 1024 total
        int r = f >> 4, q4 = (f & 15) * 4;
        float4 v = *(const float4*)(Ap + r * 64 + q4);
        ushort4 u;
        u.x = bfu(v.x); u.y = bfu(v.y); u.z = bfu(v.z); u.w = bfu(v.w);
        *(ushort4*)&Ms[r][q4] = u;             // [h=r][w=q4..]
        float4 w = *(const float4*)(Bp + r * 64 + q4);
        Ns[q4 + 0][r] = __float2bfloat16(w.x); // [d][w=r] scatter (one-time transpose)
        Ns[q4 + 1][r] = __float2bfloat16(w.y);
        Ns[q4 + 2][r] = __float2bfloat16(w.z);
        Ns[q4 + 3][r] = __float2bfloat16(w.w);
    }
    __syncthreads();
    int lane = t & 63, wv = t >> 6;
    int lrow = lane & 31, lhalf = lane >> 5;
    int hq = wv >> 1, dq = wv & 1;             // output quadrant
    f32x16 acc = {0};
#pragma unroll
    for (int ks = 0; ks < 4; ++ks) {
        bf16x8 a = *(const bf16x8*)&Ms[hq * 32 + lrow][ks * 16 + lhalf * 8];
        bf16x8 bfr = *(const bf16x8*)&Ns[dq * 32 + lrow][ks * 16 + lhalf * 8];
        acc = __builtin_amdgcn_mfma_f32_32x32x16_bf16(a, bfr, acc, 0, 0, 0);
    }
    // D layout: col(d)=lane&31, row(h)=(reg&3)+8*(reg>>2)+4*lhalf
    __hip_bfloat16* Ao = At + (long)bc * HWD + w2 * 64 + dq * 32 + lrow;
#pragma unroll
    for (int reg = 0; reg < 16; ++reg) {
        int hh = hq * 32 + (reg & 3) + 8 * (reg >> 2) + 4 * lhalf;
        Ao[(long)hh * 4096] = __float2bfloat16(acc[reg]);
    }
}

// ---------------- f v3: F[b,c,h,w,d] = sum_w2 Cc[b,c,w2,h,w] * T[b,c,w2,w,d] (bf16 out) ----
__global__ __launch_bounds__(256, 2) void k_f(const float* __restrict__ Cc,
        const float* __restrict__ T, __hip_bfloat16* __restrict__ F) {
    __shared__ float As[16][64][8];   // [kk][h][w]        32 KB
    __shared__ float Bs[16][8][68];   // [kk][w][d(+pad)]  34 KB
    int L = blockIdx.x;               // 1024 = 128 bc * 8 wt
    int xcd = L & 7, j = L >> 3;      // j 0..127
    int bc = xcd * 16 + (j >> 3), wt = j & 7;
    const float* Ab = Cc + (long)bc * HWD + wt * 8;
    const float* Bb = T + (long)bc * HWD + wt * 8 * 64;
    int t = threadIdx.x;
    int w = t & 7, h2 = t >> 3;       // h2 in 0..31
    f32x16 p00 = {0}, p01 = {0}, p02 = {0}, p03 = {0};
    f32x16 p10 = {0}, p11 = {0}, p12 = {0}, p13 = {0};

    for (int w2c = 0; w2c < 4; ++w2c) {
        __syncthreads();
        // A stage: 16 kk x 64 h x 2 half-float4 (32B contiguous per (kk,h))
#pragma unroll
        for (int i = 0; i < 8; ++i) {
            int f = i * 256 + t;                       // 0..2047
            int half = f & 1, hh = (f >> 1) & 63, kk = f >> 7;
            float4 v = *(const float4*)(Ab + (long)(w2c * 16 + kk) * 4096 + hh * 64 + half * 4);
            *(float4*)&As[kk][hh][half * 4] = v;
        }
        // B stage: 16 kk x 8 w x 16 float4 (256B contiguous per (kk,w))
#pragma unroll
        for (int i = 0; i < 8; ++i) {
            int f = i * 256 + t;
            int d4 = f & 15, ww = (f >> 4) & 7, kk = f >> 7;
            float4 v = *(const float4*)(Bb + (long)(w2c * 16 + kk) * 4096 + ww * 64 + d4 * 4);
            *(float4*)&Bs[kk][ww][d4 * 4] = v;
        }
        __syncthreads();
        for (int kk = 0; kk < 16; ++kk) {
            float a0 = As[kk][h2][w];
            float a1 = As[kk][h2 + 32][w];
            const float* br = &Bs[kk][w][0];
#pragma unroll
            for (int i = 0; i < 16; ++i) {
                p00[i] = fmaf(a0, br[i], p00[i]);
                p01[i] = fmaf(a0, br[16 + i], p01[i]);
                p02[i] = fmaf(a0, br[32 + i], p02[i]);
                p03[i] = fmaf(a0, br[48 + i], p03[i]);
                p10[i] = fmaf(a1, br[i], p10[i]);
                p11[i] = fmaf(a1, br[16 + i], p11[i]);
                p12[i] = fmaf(a1, br[32 + i], p12[i]);
                p13[i] = fmaf(a1, br[48 + i], p13[i]);
            }
        }
    }
    // store: F[bc][h][wt*8+w][d], 128B per h-row (contiguous)
    __hip_bfloat16* Fp = F + (long)bc * HWD + (long)h2 * 4096 + (wt * 8 + w) * 64;
    float tmp[16];
#pragma unroll
    for (int i = 0; i < 16; ++i) tmp[i] = p00[i];
    pack_row_bf16(Fp, tmp);
#pragma unroll
    for (int i = 0; i < 16; ++i) tmp[i] = p01[i];
    pack_row_bf16(Fp + 16, tmp);
#pragma unroll
    for (int i = 0; i < 16; ++i) tmp[i] = p02[i];
    pack_row_bf16(Fp + 32, tmp);
#pragma unroll
    for (int i = 0; i < 16; ++i) tmp[i] = p03[i];
    pack_row_bf16(Fp + 48, tmp);
    __hip_bfloat16* Fq = Fp + 32L * 4096;
#pragma unroll
    for (int i = 0; i < 16; ++i) tmp[i] = p10[i];
    pack_row_bf16(Fq, tmp);
#pragma unroll
    for (int i = 0; i < 16; ++i) tmp[i] = p11[i];
    pack_row_bf16(Fq + 16, tmp);
#pragma unroll
    for (int i = 0; i < 16; ++i) tmp[i] = p12[i];
    pack_row_bf16(Fq + 32, tmp);
#pragma unroll
    for (int i = 0; i < 16; ++i) tmp[i] = p13[i];
    pack_row_bf16(Fq + 48, tmp);
}

// ---------------- map v6 (MFMA): out[n][c] = gelu( sum_k P[n][k] Wb[k][c] + b_map[c] ) ----
// (R11-benched: double-buffered staging, T14 early-issue, 3 blocks/CU.)
__global__ __launch_bounds__(256, 3) void k_map(const float* __restrict__ x,
        const __hip_bfloat16* __restrict__ F, const __hip_bfloat16* __restrict__ At,
        const __hip_bfloat16* __restrict__ Wb, const float* __restrict__ b_map,
        float* __restrict__ out) {
    __shared__ float xs[2][16][257];          // 32896 B
    __shared__ __hip_bfloat16 fa[2][16][264]; // 16896 B

    int t = threadIdx.x;
    long n0 = (long)blockIdx.x * 256;
    int b = (int)(n0 >> 18);
    long nn0 = n0 & (HWD - 1);
    const float* xblk = x + n0 * 64;
    const __hip_bfloat16* Fb = F + (long)b * 64 * HWD + nn0;
    const __hip_bfloat16* Ab = At + (long)b * 64 * HWD + nn0;

    int lane = t & 63, wv = t >> 6;
    int lrow = lane & 31, lhalf = lane >> 5;

    // preload W fragments: B-operand frag for ks=kc is W[c][kc*16 + lhalf*8 ..+8]
    const short* Wp = (const short*)Wb;
    bf16x8 wb0[8], wb1[8];                    // static-indexed in unrolled loop only
#pragma unroll
    for (int kc = 0; kc < 8; ++kc) {
        uint4 u0 = *(const uint4*)(Wp + lrow * 128 + kc * 16 + lhalf * 8);
        uint4 u1 = *(const uint4*)(Wp + (32 + lrow) * 128 + kc * 16 + lhalf * 8);
        wb0[kc] = *(bf16x8*)&u0;
        wb1[kc] = *(bf16x8*)&u1;
    }

    f32x16 acc00 = {0}, acc01 = {0}, acc10 = {0}, acc11 = {0};

    // named staging registers (no arrays -> no scratch)
    float4 xa, xb_, xc_, xd;
    uint4 fe, ff;
    int nrA = t >> 2, j4A = (t & 3) * 4;
    int rowF0 = t >> 5, segF0 = t & 31;
    int rowF1 = (256 + t) >> 5, segF1 = t & 31;

    auto load_chunk = [&](int kc) {
        if (kc < 4) {
            xa  = *(const float4*)(xblk + (nrA +   0) * 64 + kc * 16 + j4A);
            xb_ = *(const float4*)(xblk + (nrA +  64) * 64 + kc * 16 + j4A);
            xc_ = *(const float4*)(xblk + (nrA + 128) * 64 + kc * 16 + j4A);
            xd  = *(const float4*)(xblk + (nrA + 192) * 64 + kc * 16 + j4A);
            fe = *(const uint4*)(Fb + (long)(kc * 16 + rowF0) * HWD + segF0 * 8);
            ff = *(const uint4*)(Fb + (long)(kc * 16 + rowF1) * HWD + segF1 * 8);
        } else {
            fe = *(const uint4*)(Ab + (long)((kc - 4) * 16 + rowF0) * HWD + segF0 * 8);
            ff = *(const uint4*)(Ab + (long)((kc - 4) * 16 + rowF1) * HWD + segF1 * 8);
        }
    };
    auto write_chunk = [&](int kc, int buf) {
        if (kc < 4) {
            xs[buf][j4A + 0][nrA +   0] = xa.x;
            xs[buf][j4A + 1][nrA +   0] = xa.y;
            xs[buf][j4A + 2][nrA +   0] = xa.z;
            xs[buf][j4A + 3][nrA +   0] = xa.w;
            xs[buf][j4A + 0][nrA +  64] = xb_.x;
            xs[buf][j4A + 1][nrA +  64] = xb_.y;
            xs[buf][j4A + 2][nrA +  64] = xb_.z;
            xs[buf][j4A + 3][nrA +  64] = xb_.w;
            xs[buf][j4A + 0][nrA + 128] = xc_.x;
            xs[buf][j4A + 1][nrA + 128] = xc_.y;
            xs[buf][j4A + 2][nrA + 128] = xc_.z;
            xs[buf][j4A + 3][nrA + 128] = xc_.w;
            xs[buf][j4A + 0][nrA + 192] = xd.x;
            xs[buf][j4A + 1][nrA + 192] = xd.y;
            xs[buf][j4A + 2][nrA + 192] = xd.z;
            xs[buf][j4A + 3][nrA + 192] = xd.w;
        }
        *(uint4*)&fa[buf][rowF0][segF0 * 8] = fe;
        *(uint4*)&fa[buf][rowF1][segF1 * 8] = ff;
    };

    load_chunk(0);
    write_chunk(0, 0);
    __syncthreads();

#pragma unroll
    for (int kc = 0; kc < 8; ++kc) {
        int buf = kc & 1;
        if (kc < 7) load_chunk(kc + 1);        // HBM latency hides under compute below
        // build P row t (16 bf16) in registers
        unsigned short pv[16];
        if (kc < 4) {
#pragma unroll
            for (int k2 = 0; k2 < 16; ++k2) {
                float p = xs[buf][k2][t] * __bfloat162float(fa[buf][k2][t]);
                pv[k2] = bfu(p);
            }
        } else {
#pragma unroll
            for (int k2 = 0; k2 < 16; ++k2)
                pv[k2] = *reinterpret_cast<const unsigned short*>(&fa[buf][k2][t]);
        }
        unsigned lo0 = (unsigned)pv[0]  | ((unsigned)pv[1]  << 16);
        unsigned lo1 = (unsigned)pv[2]  | ((unsigned)pv[3]  << 16);
        unsigned lo2 = (unsigned)pv[4]  | ((unsigned)pv[5]  << 16);
        unsigned lo3 = (unsigned)pv[6]  | ((unsigned)pv[7]  << 16);
        unsigned hi0 = (unsigned)pv[8]  | ((unsigned)pv[9]  << 16);
        unsigned hi1 = (unsigned)pv[10] | ((unsigned)pv[11] << 16);
        unsigned hi2 = (unsigned)pv[12] | ((unsigned)pv[13] << 16);
        unsigned hi3 = (unsigned)pv[14] | ((unsigned)pv[15] << 16);
        // A-frag assembly via intra-wave shuffles (no LDS, no barrier):
        int sl0 = lane & 31, sl1 = lane | 32;
        bool lowh = lane < 32;
        unsigned s00 = __shfl(hi0, sl0), s01 = __shfl(hi1, sl0);
        unsigned s02 = __shfl(hi2, sl0), s03 = __shfl(hi3, sl0);
        unsigned r00 = __shfl(lo0, sl1), r01 = __shfl(lo1, sl1);
        unsigned r02 = __shfl(lo2, sl1), r03 = __shfl(lo3, sl1);
        uint4 ua0, ua1;
        ua0.x = lowh ? lo0 : s00; ua0.y = lowh ? lo1 : s01;
        ua0.z = lowh ? lo2 : s02; ua0.w = lowh ? lo3 : s03;
        ua1.x = lowh ? r00 : hi0; ua1.y = lowh ? r01 : hi1;
        ua1.z = lowh ? r02 : hi2; ua1.w = lowh ? r03 : hi3;
        bf16x8 a0 = *(bf16x8*)&ua0;
        bf16x8 a1 = *(bf16x8*)&ua1;
        acc00 = __builtin_amdgcn_mfma_f32_32x32x16_bf16(a0, wb0[kc], acc00, 0, 0, 0);
        acc01 = __builtin_amdgcn_mfma_f32_32x32x16_bf16(a0, wb1[kc], acc01, 0, 0, 0);
        acc10 = __builtin_amdgcn_mfma_f32_32x32x16_bf16(a1, wb0[kc], acc10, 0, 0, 0);
        acc11 = __builtin_amdgcn_mfma_f32_32x32x16_bf16(a1, wb1[kc], acc11, 0, 0, 0);
        if (kc < 7) {
            write_chunk(kc + 1, buf ^ 1);      // buf^1's readers finished before last barrier
            __syncthreads();
        }
    }

    // epilogue: bias + exact GELU + store.
    // D layout: col(c) = lane&31, row(n) = (reg&3)+8*(reg>>2)+4*lhalf
    float bs0 = b_map[lrow];
    float bs1 = b_map[32 + lrow];
    const float inv_sqrt2 = 0.70710678118654752440f;
    float* ob = out + (n0 + wv * 64) * 64;
#pragma unroll
    for (int reg = 0; reg < 16; ++reg) {
        int nrow = (reg & 3) + 8 * (reg >> 2) + 4 * lhalf;
        float v00 = acc00[reg] + bs0;
        float v01 = acc01[reg] + bs1;
        float v10 = acc10[reg] + bs0;
        float v11 = acc11[reg] + bs1;
        v00 = 0.5f * v00 * (1.f + erff(v00 * inv_sqrt2));
        v01 = 0.5f * v01 * (1.f + erff(v01 * inv_sqrt2));
        v10 = 0.5f * v10 * (1.f + erff(v10 * inv_sqrt2));
        v11 = 0.5f * v11 * (1.f + erff(v11 * inv_sqrt2));
        ob[(long)nrow * 64 + lrow] = v00;            // lanes 0-31 + 32-63: 2x128B contig
        ob[(long)nrow * 64 + 32 + lrow] = v01;
        ob[(long)(32 + nrow) * 64 + lrow] = v10;
        ob[(long)(32 + nrow) * 64 + 32 + lrow] = v11;
    }
}

extern "C" void kernel_launch(void* const* d_in, const int* in_sizes, int n_in,
                              void* d_out, int out_size, void* d_ws, size_t ws_size,
                              hipStream_t stream) {
    const float* x     = (const float*)d_in[0];
    const float* w_t   = (const float*)d_in[1];
    const float* b_t   = (const float*)d_in[2];
    const float* w_c   = (const float*)d_in[3];
    const float* b_c   = (const float*)d_in[4];
    const float* w_map = (const float*)d_in[5];
    const float* b_map = (const float*)d_in[6];
    float* out = (float*)d_out;
    float* ws = (float*)d_ws;

    // ws layout (float offsets), ~269 MB total:
    //  [0,        16777216)  Xc bf16  (33.5M elem)  -> reused as At bf16 after convs
    //  [16777216, 33554432)  Xt bf16                -> reused as F bf16 after convs
    //  [33554432, 67108864)  T fp32
    //  [67108864, ...)       A_t bf16 (147456) | A_c bf16 (147456) | Wb bf16 (8192)
    __hip_bfloat16* Xc = (__hip_bfloat16*)ws;
    __hip_bfloat16* Xt = (__hip_bfloat16*)(ws + 16777216L);
    float* T = ws + 33554432L;
    float* Cc = out;                                     // d_out as scratch
    __hip_bfloat16* A_t = (__hip_bfloat16*)(ws + 67108864L);
    __hip_bfloat16* A_c = (__hip_bfloat16*)(ws + 67182592L);
    __hip_bfloat16* Wb = (__hip_bfloat16*)(ws + 67256320L);
    __hip_bfloat16* At_bf = Xc;                          // 67 MB, Xc dead after convs
    __hip_bfloat16* F_bf = Xt;                           // 67 MB, Xt dead after convs

    hipLaunchKernelGGL(k_prep, dim3(576), dim3(256), 0, stream, w_t, w_c, w_map, A_t, A_c, Wb);
    hipLaunchKernelGGL(k_trans_c, dim3(1024, 2), dim3(256), 0, stream, x, Xc);
    hipLaunchKernelGGL(k_trans_t, dim3(1024, 2), dim3(256), 0, stream, x, Xt);
    hipLaunchKernelGGL(k_conv_mfma, dim3(4096), dim3(256), 0, stream,
                       Xt, A_t, b_t, T, Xc, A_c, b_c, Cc);
    hipLaunchKernelGGL(k_attn, dim3(8192), dim3(256), 0, stream, Cc, T, At_bf);
    hipLaunchKernelGGL(k_f, dim3(1024), dim3(256), 0, stream, Cc, T, F_bf);
    hipLaunchKernelGGL(k_map, dim3(2048), dim3(256), 0, stream, x, F_bf, At_bf, Wb, b_map, out);
}

// Round 13
// 714.010 us; speedup vs baseline: 1.4400x; 1.0290x over previous
//
#include <hip/hip_runtime.h>
#include <hip/hip_bf16.h>
#include <math.h>

#define HWD 262144   // 64*64*64

typedef __attribute__((ext_vector_type(8))) short bf16x8;   // 8 bf16 (4 VGPRs)
typedef __attribute__((ext_vector_type(16))) float f32x16;  // MFMA 32x32 accumulator

__device__ inline unsigned short bfu(float f) {
    __hip_bfloat16 h = __float2bfloat16(f);
    return *reinterpret_cast<unsigned short*>(&h);
}

// ---------------- prep: weights -> bf16 GEMM layout A[ks 72][oc 128][kk 16]; w_map -> Wb bf16 ----
// K order: k = ((g*3+r)*3+s)*64 + z,  ks=k>>4, kk=k&15.
__global__ void k_prep(const float* __restrict__ w_t, const float* __restrict__ w_c,
                       const float* __restrict__ w_map,
                       __hip_bfloat16* __restrict__ A_t, __hip_bfloat16* __restrict__ A_c,
                       __hip_bfloat16* __restrict__ Wb) {
    int i = blockIdx.x * 256 + threadIdx.x;
    if (i < 147456) {
        int kk = i & 15, oc = (i >> 4) & 127, ks = i >> 11;
        int z4 = ks & 3, kq = ks >> 2;          // kq = (g*3+r)*3+s in [0,18)
        int g = kq / 9, tap = kq - 9 * g;       // tap = r*3+s
        int z = z4 * 16 + kk;
        // w_t (128,2,64,3,3): ((o*2+g)*64+kh)*9 + tap,  z=kh
        A_t[i] = __float2bfloat16(w_t[((oc * 2 + g) * 64 + z) * 9 + tap]);
        // w_c (128,2,3,3,64): ((o*2+g)*9+tap)*64 + kd,  z=kd
        A_c[i] = __float2bfloat16(w_c[((oc * 2 + g) * 9 + tap) * 64 + z]);
    }
    if (i < 8192) {
        Wb[i] = __float2bfloat16(w_map[i]);   // w_map is (C,2C) row-major = [c][k]
    }
}

__device__ inline void pack_row_bf16(__hip_bfloat16* dst, const float* src) {
    unsigned short u[16];
#pragma unroll
    for (int j = 0; j < 16; ++j) u[j] = bfu(src[j]);
    uint4* q = reinterpret_cast<uint4*>(dst);
    q[0] = *reinterpret_cast<const uint4*>(&u[0]);
    q[1] = *reinterpret_cast<const uint4*>(&u[8]);
}

// ---------------- transpose x (B,N,C) -> Xc bf16, z4-plane layout [cg][z4][h*w][16] ------------
__global__ void k_trans_c(const float* __restrict__ x, __hip_bfloat16* __restrict__ Xc) {
    __shared__ unsigned short tile[256][68];
    int b = blockIdx.y;
    long n0 = (long)blockIdx.x * 256;
    int t = threadIdx.x;
    const float4* xp4 = (const float4*)(x + ((long)b * HWD + n0) * 64);
#pragma unroll
    for (int i = 0; i < 16; ++i) {
        int f4i = i * 256 + t;
        float4 v = xp4[f4i];
        int nl = f4i >> 4, c4 = (f4i & 15) * 4;
        ushort4 u;
        u.x = bfu(v.x); u.y = bfu(v.y); u.z = bfu(v.z); u.w = bfu(v.w);
        *(ushort4*)&tile[nl][c4] = u;
    }
    __syncthreads();
    int c = t >> 2, hwl = t & 3;
    int hw0 = blockIdx.x * 4;
    __hip_bfloat16* dst0 = Xc + (long)(b * 64 + c) * HWD + (long)(hw0 + hwl) * 16;
#pragma unroll
    for (int z4 = 0; z4 < 4; ++z4) {
        unsigned short u[16];
#pragma unroll
        for (int j = 0; j < 16; ++j) u[j] = tile[hwl * 64 + z4 * 16 + j][c];
        __hip_bfloat16* dst = dst0 + z4 * 65536;
        *(uint4*)dst = *(const uint4*)&u[0];
        *(uint4*)(dst + 8) = *(const uint4*)&u[8];
    }
}

// ---------------- transpose x -> Xt bf16, z4-plane layout [cg][z4][w*d][16] (inner 16 = h) -----
__global__ void k_trans_t(const float* __restrict__ x, __hip_bfloat16* __restrict__ Xt) {
    __shared__ unsigned short tile[256][68];   // [wdl*64+h][c]
    int b = blockIdx.y;
    int wd0 = blockIdx.x * 4;
    int t = threadIdx.x;
    const float* xb = x + (long)b * HWD * 64 + (long)wd0 * 64;
#pragma unroll
    for (int i = 0; i < 16; ++i) {
        int idx = i * 256 + t;              // float4 id over 64 h x 64 f
        int h = idx >> 6, f = idx & 63;     // per h: 4 wd x 64 c = 1KB contiguous
        float4 v = *(const float4*)(xb + (long)h * 262144 + f * 4);
        int wdl = f >> 4, c4 = (f & 15) * 4;
        ushort4 u;
        u.x = bfu(v.x); u.y = bfu(v.y); u.z = bfu(v.z); u.w = bfu(v.w);
        *(ushort4*)&tile[wdl * 64 + h][c4] = u;
    }
    __syncthreads();
    int c = t >> 2, wdl = t & 3;
    __hip_bfloat16* dst0 = Xt + (long)(b * 64 + c) * HWD + (long)(wd0 + wdl) * 16;
#pragma unroll
    for (int z4 = 0; z4 < 4; ++z4) {
        unsigned short u[16];
#pragma unroll
        for (int j = 0; j < 16; ++j) u[j] = tile[wdl * 64 + z4 * 16 + j][c];
        __hip_bfloat16* dst = dst0 + z4 * 65536;
        *(uint4*)dst = *(const uint4*)&u[0];
        *(uint4*)(dst + 8) = *(const uint4*)&u[8];
    }
}

// ---------------- unified MFMA conv v7: R9 structure, both convs MERGED in one dispatch -------
__global__ __launch_bounds__(256, 3) void k_conv_mfma(
        const __hip_bfloat16* __restrict__ Xt, const __hip_bfloat16* __restrict__ At_,
        const float* __restrict__ bt, float* __restrict__ OutT,
        const __hip_bfloat16* __restrict__ Xc, const __hip_bfloat16* __restrict__ Ac_,
        const float* __restrict__ bcb, float* __restrict__ OutC) {
    int Lfull = blockIdx.x;                   // 4096 = 2 halves x 2048
    int halfk = Lfull >> 11;
    int L = Lfull & 2047;                     // 2048 = 64 grp * 32 pt
    const __hip_bfloat16* X = halfk ? Xc : Xt;
    const __hip_bfloat16* Aglob = halfk ? Ac_ : At_;
    const float* bias = halfk ? bcb : bt;
    float* Out = halfk ? OutC : OutT;

    int grp = (L & 7) * 8 + ((L >> 3) >> 5);  // XCD r handles grps [r*8, r*8+8)
    int pt = (L >> 3) & 31;
    int b = grp >> 5, ch = grp & 31;
    int p0 = pt * 2;
    const short* Xg = (const short*)(X + ((long)(b * 64 + 2 * ch)) * HWD);
    const short* Ag = (const short*)Aglob;
    int t = threadIdx.x;
    int lane = t & 63, wv = t >> 6;
    int O0 = (wv >> 1) * 64;              // wave oc base
    int N0 = (wv & 1) * 64;               // wave n base
    int lrow = lane & 31, lq = lane >> 5;

    // LDS: [buf][z4][khalf][128 rows x 8 shorts] = 32 KB
    __shared__ __align__(16) short Bsm[2][4][2][1024];

    f32x16 acc00 = {0}, acc01 = {0}, acc10 = {0}, acc11 = {0};

    int srow = t >> 1, shalf = t & 1;
    int spr = srow >> 6, sq = srow & 63;  // (p-row, q) of the staged B-row
    const uint4 zero4 = {0u, 0u, 0u, 0u};
    uint4 ld0, ld1, ld2, ld3;             // named (no arrays -> no scratch)

    auto stage_load = [&](int kq) {
        int g = (kq >= 9) ? 1 : 0;
        int tap = kq - 9 * g;
        int r = tap / 3, s = tap - 3 * r;
        int pp = p0 + spr + r - 1, qq = sq + s - 1;
        bool ok = ((unsigned)pp < 64u) && ((unsigned)qq < 64u);
        const short* px = Xg + (long)g * HWD + (pp * 64 + qq) * 16 + shalf * 8;
        ld0 = ok ? *(const uint4*)(px)           : zero4;
        ld1 = ok ? *(const uint4*)(px + 65536)   : zero4;
        ld2 = ok ? *(const uint4*)(px + 131072)  : zero4;
        ld3 = ok ? *(const uint4*)(px + 196608)  : zero4;
    };
    auto stage_write = [&](int buf) {
        *(uint4*)&Bsm[buf][0][shalf][srow * 8] = ld0;
        *(uint4*)&Bsm[buf][1][shalf][srow * 8] = ld1;
        *(uint4*)&Bsm[buf][2][shalf][srow * 8] = ld2;
        *(uint4*)&Bsm[buf][3][shalf][srow * 8] = ld3;
    };

    stage_load(0);
    stage_write(0);
    __syncthreads();

    int buf = 0;
    for (int kq = 0; kq < 18; ++kq) {
        if (kq < 17) stage_load(kq + 1);       // in flight across the 16-MFMA cluster
#pragma unroll
        for (int z4 = 0; z4 < 4; ++z4) {
            int ks = kq * 4 + z4;
            const short* Apk = Ag + ks * 2048 + (O0 + lrow) * 16 + lq * 8;
            uint4 a0u = *(const uint4*)(Apk);
            uint4 a1u = *(const uint4*)(Apk + 512);
            bf16x8 a0 = *(bf16x8*)&a0u;
            bf16x8 a1 = *(bf16x8*)&a1u;
            bf16x8 b0 = *(const bf16x8*)&Bsm[buf][z4][lq][(N0 + lrow) * 8];
            bf16x8 b1 = *(const bf16x8*)&Bsm[buf][z4][lq][(N0 + 32 + lrow) * 8];
            acc00 = __builtin_amdgcn_mfma_f32_32x32x16_bf16(a0, b0, acc00, 0, 0, 0);
            acc01 = __builtin_amdgcn_mfma_f32_32x32x16_bf16(a0, b1, acc01, 0, 0, 0);
            acc10 = __builtin_amdgcn_mfma_f32_32x32x16_bf16(a1, b0, acc10, 0, 0, 0);
            acc11 = __builtin_amdgcn_mfma_f32_32x32x16_bf16(a1, b1, acc11, 0, 0, 0);
        }
        if (kq < 17) {
            stage_write(buf ^ 1);
            __syncthreads();
            buf ^= 1;
        }
    }

    // store: C/D layout col=lane&31, row=(reg&3)+8*(reg>>2)+4*(lane>>5)
    long base0 = ((long)(b * 64 + 2 * ch)) * HWD + (long)p0 * 64;
    int n0l = N0 + lrow, n1l = N0 + 32 + lrow;
    long noff0 = (long)(n0l >> 6) * 64 + (n0l & 63);
    long noff1 = (long)(n1l >> 6) * 64 + (n1l & 63);
#pragma unroll
    for (int reg = 0; reg < 16; ++reg) {
        int row = (reg & 3) + 8 * (reg >> 2) + 4 * lq;
        int oc0 = O0 + row, oc1 = O0 + 32 + row;
        long cb0 = base0 + (long)(oc0 >> 6) * HWD + (long)(oc0 & 63) * 4096;
        long cb1 = base0 + (long)(oc1 >> 6) * HWD + (long)(oc1 & 63) * 4096;
        float bs0 = bias[oc0], bs1 = bias[oc1];
        Out[cb0 + noff0] = acc00[reg] + bs0;
        Out[cb0 + noff1] = acc01[reg] + bs0;
        Out[cb1 + noff0] = acc10[reg] + bs1;
        Out[cb1 + noff1] = acc11[reg] + bs1;
    }
}

// ---------------- attn v3 (MFMA): At[bc,h,w2,d] = sum_w Cc[bc,w2,h,w] * T[bc,w2,w,d] ----------
__global__ __launch_bounds__(256) void k_attn(const float* __restrict__ Cc,
        const float* __restrict__ T, __hip_bfloat16* __restrict__ At) {
    __shared__ __align__(16) __hip_bfloat16 Ms[64][72];   // [h][w] 9216B, 144B rows (16B-mult)
    __shared__ __align__(16) __hip_bfloat16 Ns[64][72];   // [d][w] 9216B, transposed T
    int L = blockIdx.x;                        // 8192 = 128 bc * 64 w2
    int xcd = L & 7, j = L >> 3;
    int bc = xcd * 16 + (j >> 6), w2 = j & 63;
    const float* Ap = Cc + ((long)bc * 64 + w2) * 4096;
    const float* Bp = T + ((long)bc * 64 + w2) * 4096;
    int t = threadIdx.x;
#pragma unroll
    for (int i = 0; i < 4; ++i) {
        int f = i * 256 + t;                   // float4 id, 1024 total
        int r = f >> 4, q4 = (f & 15) * 4;
        float4 v = *(const float4*)(Ap + r * 64 + q4);
        ushort4 u;
        u.x = bfu(v.x); u.y = bfu(v.y); u.z = bfu(v.z); u.w = bfu(v.w);
        *(ushort4*)&Ms[r][q4] = u;             // [h=r][w=q4..]
        float4 w = *(const float4*)(Bp + r * 64 + q4);
        Ns[q4 + 0][r] = __float2bfloat16(w.x); // [d][w=r] scatter (one-time transpose)
        Ns[q4 + 1][r] = __float2bfloat16(w.y);
        Ns[q4 + 2][r] = __float2bfloat16(w.z);
        Ns[q4 + 3][r] = __float2bfloat16(w.w);
    }
    __syncthreads();
    int lane = t & 63, wv = t >> 6;
    int lrow = lane & 31, lhalf = lane >> 5;
    int hq = wv >> 1, dq = wv & 1;             // output quadrant
    f32x16 acc = {0};
#pragma unroll
    for (int ks = 0; ks < 4; ++ks) {
        bf16x8 a = *(const bf16x8*)&Ms[hq * 32 + lrow][ks * 16 + lhalf * 8];
        bf16x8 bfr = *(const bf16x8*)&Ns[dq * 32 + lrow][ks * 16 + lhalf * 8];
        acc = __builtin_amdgcn_mfma_f32_32x32x16_bf16(a, bfr, acc, 0, 0, 0);
    }
    // D layout: col(d)=lane&31, row(h)=(reg&3)+8*(reg>>2)+4*lhalf
    __hip_bfloat16* Ao = At + (long)bc * HWD + w2 * 64 + dq * 32 + lrow;
#pragma unroll
    for (int reg = 0; reg < 16; ++reg) {
        int hh = hq * 32 + (reg & 3) + 8 * (reg >> 2) + 4 * lhalf;
        Ao[(long)hh * 4096] = __float2bfloat16(acc[reg]);
    }
}

// ---------------- f v4 (MFMA): F[bc,h,w,d] = sum_w2 Cc[bc,w2,h,w] * T[bc,w2,w,d] --------------
// R12: k_attn's MFMA conversion validated (absmax unchanged) -> same recipe for k_f, the last
// VALU GEMM. Block = (bc, 8-w tile), 512 thr = 8 waves, ONE WAVE PER W. Per w2-chunk of 16:
// stage As[w][h][w2] (transpose in staging; 24-short rows = 48B -> <=4-way conflicts, same as
// conv Bsm) and Ns[w][d][w2]; 4 MFMAs/wave (output quadrants). 16 MFMA + 32 b128-read per
// wave total replaces v3's ~4k LDS-bound VALU cycles. Memory-bound: ~335MB -> ~60us floor.
__global__ __launch_bounds__(512, 4) void k_f(const float* __restrict__ Cc,
        const float* __restrict__ T, __hip_bfloat16* __restrict__ F) {
    __shared__ __align__(16) __hip_bfloat16 As[8][64][24];  // [w][h][w2+pad] 24576B
    __shared__ __align__(16) __hip_bfloat16 Ns[8][64][24];  // [w][d][w2+pad] 24576B
    int L = blockIdx.x;               // 1024 = 128 bc * 8 wt
    int xcd = L & 7, j = L >> 3;      // j 0..127
    int bc = xcd * 16 + (j >> 3), wt = j & 7;
    const float* Ab = Cc + (long)bc * HWD;
    const float* Bb = T + (long)bc * HWD;
    int t = threadIdx.x;
    int lane = t & 63, wv = t >> 6;   // wv = local w (0..7)
    int lrow = lane & 31, lhalf = lane >> 5;
    f32x16 acc00 = {0}, acc01 = {0}, acc10 = {0}, acc11 = {0};

    for (int w2c = 0; w2c < 4; ++w2c) {
        __syncthreads();
        // A stage: Cc[kk][hh][wt*8 + half*4 ..+4], 32B-contiguous float4 pairs (v3 pattern),
        // transposed into As[w][h][kk].
#pragma unroll
        for (int i = 0; i < 4; ++i) {
            int f = i * 512 + t;                        // 0..2047
            int half = f & 1, hh = (f >> 1) & 63, kk = f >> 7;
            float4 v = *(const float4*)(Ab + (long)(w2c * 16 + kk) * 4096 + hh * 64 + wt * 8 + half * 4);
            As[half * 4 + 0][hh][kk] = __float2bfloat16(v.x);
            As[half * 4 + 1][hh][kk] = __float2bfloat16(v.y);
            As[half * 4 + 2][hh][kk] = __float2bfloat16(v.z);
            As[half * 4 + 3][hh][kk] = __float2bfloat16(v.w);
        }
        // B stage: T[kk][wt*8+ww][d], fully coalesced float4 over d, transposed into Ns[w][d][kk].
#pragma unroll
        for (int i = 0; i < 4; ++i) {
            int f = i * 512 + t;
            int d4 = f & 15, ww = (f >> 4) & 7, kk = f >> 7;
            float4 v = *(const float4*)(Bb + (long)(w2c * 16 + kk) * 4096 + (wt * 8 + ww) * 64 + d4 * 4);
            Ns[ww][d4 * 4 + 0][kk] = __float2bfloat16(v.x);
            Ns[ww][d4 * 4 + 1][kk] = __float2bfloat16(v.y);
            Ns[ww][d4 * 4 + 2][kk] = __float2bfloat16(v.z);
            Ns[ww][d4 * 4 + 3][kk] = __float2bfloat16(v.w);
        }
        __syncthreads();
        bf16x8 a0 = *(const bf16x8*)&As[wv][lrow][lhalf * 8];
        bf16x8 a1 = *(const bf16x8*)&As[wv][32 + lrow][lhalf * 8];
        bf16x8 b0 = *(const bf16x8*)&Ns[wv][lrow][lhalf * 8];
        bf16x8 b1 = *(const bf16x8*)&Ns[wv][32 + lrow][lhalf * 8];
        acc00 = __builtin_amdgcn_mfma_f32_32x32x16_bf16(a0, b0, acc00, 0, 0, 0);
        acc01 = __builtin_amdgcn_mfma_f32_32x32x16_bf16(a0, b1, acc01, 0, 0, 0);
        acc10 = __builtin_amdgcn_mfma_f32_32x32x16_bf16(a1, b0, acc10, 0, 0, 0);
        acc11 = __builtin_amdgcn_mfma_f32_32x32x16_bf16(a1, b1, acc11, 0, 0, 0);
    }
    // store: F[bc][h][wt*8+wv][d]; D layout col(d)=lane&31, row(h)=(reg&3)+8*(reg>>2)+4*lhalf
    __hip_bfloat16* Fp = F + (long)bc * HWD + (wt * 8 + wv) * 64;
#pragma unroll
    for (int reg = 0; reg < 16; ++reg) {
        int row = (reg & 3) + 8 * (reg >> 2) + 4 * lhalf;
        Fp[(long)row * 4096 + lrow]             = __float2bfloat16(acc00[reg]);
        Fp[(long)row * 4096 + 32 + lrow]        = __float2bfloat16(acc01[reg]);
        Fp[(long)(32 + row) * 4096 + lrow]      = __float2bfloat16(acc10[reg]);
        Fp[(long)(32 + row) * 4096 + 32 + lrow] = __float2bfloat16(acc11[reg]);
    }
}

// ---------------- map v6 (MFMA): out[n][c] = gelu( sum_k P[n][k] Wb[k][c] + b_map[c] ) ----
// (R11-benched: double-buffered staging, T14 early-issue, 3 blocks/CU.)
__global__ __launch_bounds__(256, 3) void k_map(const float* __restrict__ x,
        const __hip_bfloat16* __restrict__ F, const __hip_bfloat16* __restrict__ At,
        const __hip_bfloat16* __restrict__ Wb, const float* __restrict__ b_map,
        float* __restrict__ out) {
    __shared__ float xs[2][16][257];          // 32896 B
    __shared__ __hip_bfloat16 fa[2][16][264]; // 16896 B

    int t = threadIdx.x;
    long n0 = (long)blockIdx.x * 256;
    int b = (int)(n0 >> 18);
    long nn0 = n0 & (HWD - 1);
    const float* xblk = x + n0 * 64;
    const __hip_bfloat16* Fb = F + (long)b * 64 * HWD + nn0;
    const __hip_bfloat16* Ab = At + (long)b * 64 * HWD + nn0;

    int lane = t & 63, wv = t >> 6;
    int lrow = lane & 31, lhalf = lane >> 5;

    // preload W fragments: B-operand frag for ks=kc is W[c][kc*16 + lhalf*8 ..+8]
    const short* Wp = (const short*)Wb;
    bf16x8 wb0[8], wb1[8];                    // static-indexed in unrolled loop only
#pragma unroll
    for (int kc = 0; kc < 8; ++kc) {
        uint4 u0 = *(const uint4*)(Wp + lrow * 128 + kc * 16 + lhalf * 8);
        uint4 u1 = *(const uint4*)(Wp + (32 + lrow) * 128 + kc * 16 + lhalf * 8);
        wb0[kc] = *(bf16x8*)&u0;
        wb1[kc] = *(bf16x8*)&u1;
    }

    f32x16 acc00 = {0}, acc01 = {0}, acc10 = {0}, acc11 = {0};

    // named staging registers (no arrays -> no scratch)
    float4 xa, xb_, xc_, xd;
    uint4 fe, ff;
    int nrA = t >> 2, j4A = (t & 3) * 4;
    int rowF0 = t >> 5, segF0 = t & 31;
    int rowF1 = (256 + t) >> 5, segF1 = t & 31;

    auto load_chunk = [&](int kc) {
        if (kc < 4) {
            xa  = *(const float4*)(xblk + (nrA +   0) * 64 + kc * 16 + j4A);
            xb_ = *(const float4*)(xblk + (nrA +  64) * 64 + kc * 16 + j4A);
            xc_ = *(const float4*)(xblk + (nrA + 128) * 64 + kc * 16 + j4A);
            xd  = *(const float4*)(xblk + (nrA + 192) * 64 + kc * 16 + j4A);
            fe = *(const uint4*)(Fb + (long)(kc * 16 + rowF0) * HWD + segF0 * 8);
            ff = *(const uint4*)(Fb + (long)(kc * 16 + rowF1) * HWD + segF1 * 8);
        } else {
            fe = *(const uint4*)(Ab + (long)((kc - 4) * 16 + rowF0) * HWD + segF0 * 8);
            ff = *(const uint4*)(Ab + (long)((kc - 4) * 16 + rowF1) * HWD + segF1 * 8);
        }
    };
    auto write_chunk = [&](int kc, int buf) {
        if (kc < 4) {
            xs[buf][j4A + 0][nrA +   0] = xa.x;
            xs[buf][j4A + 1][nrA +   0] = xa.y;
            xs[buf][j4A + 2][nrA +   0] = xa.z;
            xs[buf][j4A + 3][nrA +   0] = xa.w;
            xs[buf][j4A + 0][nrA +  64] = xb_.x;
            xs[buf][j4A + 1][nrA +  64] = xb_.y;
            xs[buf][j4A + 2][nrA +  64] = xb_.z;
            xs[buf][j4A + 3][nrA +  64] = xb_.w;
            xs[buf][j4A + 0][nrA + 128] = xc_.x;
            xs[buf][j4A + 1][nrA + 128] = xc_.y;
            xs[buf][j4A + 2][nrA + 128] = xc_.z;
            xs[buf][j4A + 3][nrA + 128] = xc_.w;
            xs[buf][j4A + 0][nrA + 192] = xd.x;
            xs[buf][j4A + 1][nrA + 192] = xd.y;
            xs[buf][j4A + 2][nrA + 192] = xd.z;
            xs[buf][j4A + 3][nrA + 192] = xd.w;
        }
        *(uint4*)&fa[buf][rowF0][segF0 * 8] = fe;
        *(uint4*)&fa[buf][rowF1][segF1 * 8] = ff;
    };

    load_chunk(0);
    write_chunk(0, 0);
    __syncthreads();

#pragma unroll
    for (int kc = 0; kc < 8; ++kc) {
        int buf = kc & 1;
        if (kc < 7) load_chunk(kc + 1);        // HBM latency hides under compute below
        // build P row t (16 bf16) in registers
        unsigned short pv[16];
        if (kc < 4) {
#pragma unroll
            for (int k2 = 0; k2 < 16; ++k2) {
                float p = xs[buf][k2][t] * __bfloat162float(fa[buf][k2][t]);
                pv[k2] = bfu(p);
            }
        } else {
#pragma unroll
            for (int k2 = 0; k2 < 16; ++k2)
                pv[k2] = *reinterpret_cast<const unsigned short*>(&fa[buf][k2][t]);
        }
        unsigned lo0 = (unsigned)pv[0]  | ((unsigned)pv[1]  << 16);
        unsigned lo1 = (unsigned)pv[2]  | ((unsigned)pv[3]  << 16);
        unsigned lo2 = (unsigned)pv[4]  | ((unsigned)pv[5]  << 16);
        unsigned lo3 = (unsigned)pv[6]  | ((unsigned)pv[7]  << 16);
        unsigned hi0 = (unsigned)pv[8]  | ((unsigned)pv[9]  << 16);
        unsigned hi1 = (unsigned)pv[10] | ((unsigned)pv[11] << 16);
        unsigned hi2 = (unsigned)pv[12] | ((unsigned)pv[13] << 16);
        unsigned hi3 = (unsigned)pv[14] | ((unsigned)pv[15] << 16);
        // A-frag assembly via intra-wave shuffles (no LDS, no barrier):
        int sl0 = lane & 31, sl1 = lane | 32;
        bool lowh = lane < 32;
        unsigned s00 = __shfl(hi0, sl0), s01 = __shfl(hi1, sl0);
        unsigned s02 = __shfl(hi2, sl0), s03 = __shfl(hi3, sl0);
        unsigned r00 = __shfl(lo0, sl1), r01 = __shfl(lo1, sl1);
        unsigned r02 = __shfl(lo2, sl1), r03 = __shfl(lo3, sl1);
        uint4 ua0, ua1;
        ua0.x = lowh ? lo0 : s00; ua0.y = lowh ? lo1 : s01;
        ua0.z = lowh ? lo2 : s02; ua0.w = lowh ? lo3 : s03;
        ua1.x = lowh ? r00 : hi0; ua1.y = lowh ? r01 : hi1;
        ua1.z = lowh ? r02 : hi2; ua1.w = lowh ? r03 : hi3;
        bf16x8 a0 = *(bf16x8*)&ua0;
        bf16x8 a1 = *(bf16x8*)&ua1;
        acc00 = __builtin_amdgcn_mfma_f32_32x32x16_bf16(a0, wb0[kc], acc00, 0, 0, 0);
        acc01 = __builtin_amdgcn_mfma_f32_32x32x16_bf16(a0, wb1[kc], acc01, 0, 0, 0);
        acc10 = __builtin_amdgcn_mfma_f32_32x32x16_bf16(a1, wb0[kc], acc10, 0, 0, 0);
        acc11 = __builtin_amdgcn_mfma_f32_32x32x16_bf16(a1, wb1[kc], acc11, 0, 0, 0);
        if (kc < 7) {
            write_chunk(kc + 1, buf ^ 1);      // buf^1's readers finished before last barrier
            __syncthreads();
        }
    }

    // epilogue: bias + exact GELU + store.
    // D layout: col(c) = lane&31, row(n) = (reg&3)+8*(reg>>2)+4*lhalf
    float bs0 = b_map[lrow];
    float bs1 = b_map[32 + lrow];
    const float inv_sqrt2 = 0.70710678118654752440f;
    float* ob = out + (n0 + wv * 64) * 64;
#pragma unroll
    for (int reg = 0; reg < 16; ++reg) {
        int nrow = (reg & 3) + 8 * (reg >> 2) + 4 * lhalf;
        float v00 = acc00[reg] + bs0;
        float v01 = acc01[reg] + bs1;
        float v10 = acc10[reg] + bs0;
        float v11 = acc11[reg] + bs1;
        v00 = 0.5f * v00 * (1.f + erff(v00 * inv_sqrt2));
        v01 = 0.5f * v01 * (1.f + erff(v01 * inv_sqrt2));
        v10 = 0.5f * v10 * (1.f + erff(v10 * inv_sqrt2));
        v11 = 0.5f * v11 * (1.f + erff(v11 * inv_sqrt2));
        ob[(long)nrow * 64 + lrow] = v00;            // lanes 0-31 + 32-63: 2x128B contig
        ob[(long)nrow * 64 + 32 + lrow] = v01;
        ob[(long)(32 + nrow) * 64 + lrow] = v10;
        ob[(long)(32 + nrow) * 64 + 32 + lrow] = v11;
    }
}

extern "C" void kernel_launch(void* const* d_in, const int* in_sizes, int n_in,
                              void* d_out, int out_size, void* d_ws, size_t ws_size,
                              hipStream_t stream) {
    const float* x     = (const float*)d_in[0];
    const float* w_t   = (const float*)d_in[1];
    const float* b_t   = (const float*)d_in[2];
    const float* w_c   = (const float*)d_in[3];
    const float* b_c   = (const float*)d_in[4];
    const float* w_map = (const float*)d_in[5];
    const float* b_map = (const float*)d_in[6];
    float* out = (float*)d_out;
    float* ws = (float*)d_ws;

    // ws layout (float offsets), ~269 MB total:
    //  [0,        16777216)  Xc bf16  (33.5M elem)  -> reused as At bf16 after convs
    //  [16777216, 33554432)  Xt bf16                -> reused as F bf16 after convs
    //  [33554432, 67108864)  T fp32
    //  [67108864, ...)       A_t bf16 (147456) | A_c bf16 (147456) | Wb bf16 (8192)
    __hip_bfloat16* Xc = (__hip_bfloat16*)ws;
    __hip_bfloat16* Xt = (__hip_bfloat16*)(ws + 16777216L);
    float* T = ws + 33554432L;
    float* Cc = out;                                     // d_out as scratch
    __hip_bfloat16* A_t = (__hip_bfloat16*)(ws + 67108864L);
    __hip_bfloat16* A_c = (__hip_bfloat16*)(ws + 67182592L);
    __hip_bfloat16* Wb = (__hip_bfloat16*)(ws + 67256320L);
    __hip_bfloat16* At_bf = Xc;                          // 67 MB, Xc dead after convs
    __hip_bfloat16* F_bf = Xt;                           // 67 MB, Xt dead after convs

    hipLaunchKernelGGL(k_prep, dim3(576), dim3(256), 0, stream, w_t, w_c, w_map, A_t, A_c, Wb);
    hipLaunchKernelGGL(k_trans_c, dim3(1024, 2), dim3(256), 0, stream, x, Xc);
    hipLaunchKernelGGL(k_trans_t, dim3(1024, 2), dim3(256), 0, stream, x, Xt);
    hipLaunchKernelGGL(k_conv_mfma, dim3(4096), dim3(256), 0, stream,
                       Xt, A_t, b_t, T, Xc, A_c, b_c, Cc);
    hipLaunchKernelGGL(k_attn, dim3(8192), dim3(256), 0, stream, Cc, T, At_bf);
    hipLaunchKernelGGL(k_f, dim3(1024), dim3(512), 0, stream, Cc, T, F_bf);
    hipLaunchKernelGGL(k_map, dim3(2048), dim3(256), 0, stream, x, F_bf, At_bf, Wb, b_map, out);
}